// Round 7
// baseline (166.945 us; speedup 1.0000x reference)
//
#include <hip/hip_runtime.h>
#include <hip/hip_bf16.h>

#define N_NODES 50000
#define N_EDGES 800000
#define D 128
#define N_PAD 50176          // 392 * 128
#define NBUCKET 392          // dst >> 7 (max used: 390)
#define SCAN_BLOCKS 49
#define PCHUNK 4096
#define NPBLK ((N_EDGES + PCHUNK - 1) / PCHUNK)  // 196

typedef __attribute__((ext_vector_type(8))) short bf16x8;
typedef __attribute__((ext_vector_type(4))) float f32x4;

__device__ inline unsigned short f2bf(float f) {
  unsigned u = __float_as_uint(f);
  unsigned r = (u + 0x7FFFu + ((u >> 16) & 1u)) >> 16;
  return (unsigned short)r;
}

// ---------------- prep: h f32 -> 4 quarter-tables (XCD-sized), + histogram ----
// h_split[q][n][16 uints] : quarter q holds channels [32q, 32q+32), 3.2MB each.
__global__ __launch_bounds__(256) void prep_kernel(const float* __restrict__ h,
                                                   unsigned* __restrict__ h_split,
                                                   const int* __restrict__ dst,
                                                   int* __restrict__ count) {
  int i = blockIdx.x * blockDim.x + threadIdx.x;
  if (i < N_NODES * D / 4) {
    float4 f = ((const float4*)h)[i];
    unsigned lo = ((unsigned)f2bf(f.y) << 16) | f2bf(f.x);
    unsigned hi = ((unsigned)f2bf(f.w) << 16) | f2bf(f.z);
    int n = i >> 5, r = i & 31;           // r: which float4 within the row
    int q = r >> 3, jq = r & 7;           // quarter, uint2-index within quarter
    ((uint2*)h_split)[((size_t)q * N_NODES + n) * 8 + jq] = make_uint2(lo, hi);
  }
  if (i < N_EDGES) atomicAdd(&count[dst[i]], 1);
}

// ---------------- scan of per-node counts (3 dispatches) ----------------

__global__ __launch_bounds__(256) void scan_part1(const int4* __restrict__ count4,
                                                  int* __restrict__ blocksum) {
  __shared__ int wsum[4];
  int b = blockIdx.x, t = threadIdx.x;
  int lane = t & 63, wid = t >> 6;
  int4 v = count4[b * 256 + t];
  int s = v.x + v.y + v.z + v.w;
#pragma unroll
  for (int off = 32; off >= 1; off >>= 1) s += __shfl_xor(s, off, 64);
  if (lane == 0) wsum[wid] = s;
  __syncthreads();
  if (t == 0) blocksum[b] = wsum[0] + wsum[1] + wsum[2] + wsum[3];
}

// wave 0: scan 49 block sums; all 1024 threads: convert W to bf16.
__global__ __launch_bounds__(1024) void scan2_convw(const int* __restrict__ blocksum,
                                                    int* __restrict__ blockoff,
                                                    const float4* __restrict__ Wm4,
                                                    ushort4* __restrict__ W4) {
  int t = threadIdx.x;
  if (t < 64) {
    int v = (t < SCAN_BLOCKS) ? blocksum[t] : 0;
    int incl = v;
#pragma unroll
    for (int off = 1; off < 64; off <<= 1) {
      int y = __shfl_up(incl, off, 64);
      if (t >= off) incl += y;
    }
    if (t < SCAN_BLOCKS) blockoff[t] = incl - v;
  }
  for (int i = t; i < D * D / 4; i += 1024) {
    float4 f = Wm4[i];
    ushort4 o;
    o.x = f2bf(f.x); o.y = f2bf(f.y); o.z = f2bf(f.z); o.w = f2bf(f.w);
    W4[i] = o;
  }
}

// row_start (padded; flat past N_NODES) + bucket cursors gcursor[b]=row_start[b*128]
__global__ __launch_bounds__(256) void scan_part3(const int4* __restrict__ count4,
                                                  const int* __restrict__ blockoff,
                                                  int4* __restrict__ row4,
                                                  int* __restrict__ gcursor) {
  __shared__ int wsum[4];
  int b = blockIdx.x, t = threadIdx.x;
  int lane = t & 63, wid = t >> 6;
  int4 v = count4[b * 256 + t];
  int s = v.x + v.y + v.z + v.w;
  int incl = s;
#pragma unroll
  for (int off = 1; off < 64; off <<= 1) {
    int y = __shfl_up(incl, off, 64);
    if (lane >= off) incl += y;
  }
  if (lane == 63) wsum[wid] = incl;
  __syncthreads();
  int woff = 0;
#pragma unroll
  for (int i = 0; i < 4; ++i) woff += (i < wid) ? wsum[i] : 0;
  int excl = incl - s + woff + blockoff[b];
  int4 p;
  p.x = excl;
  p.y = p.x + v.x;
  p.z = p.y + v.y;
  p.w = p.z + v.z;
  row4[b * 256 + t] = p;
  int node = b * 1024 + t * 4;
  if ((node & 127) == 0) gcursor[node >> 7] = p.x;
}

// ---------------- phase 1: LDS-staged partition by 128-node bucket -----------
// packed record: [src:16 | node_local:7 | w_q9:9]
__global__ __launch_bounds__(256) void partition_kernel(const int* __restrict__ src,
                                                        const int* __restrict__ dst,
                                                        const float* __restrict__ w,
                                                        int* __restrict__ gcursor,
                                                        unsigned* __restrict__ csr4) {
  __shared__ int lhist[NBUCKET];
  __shared__ int lstart[NBUCKET];
  __shared__ int lcur[NBUCKET];
  __shared__ int gbase[NBUCKET];
  __shared__ unsigned staged_v[PCHUNK];
  __shared__ unsigned short staged_b[PCHUNK];
  int t = threadIdx.x;
  int e0 = blockIdx.x * PCHUNK;
  int nch = N_EDGES - e0; if (nch > PCHUNK) nch = PCHUNK;

  for (int i = t; i < NBUCKET; i += 256) lhist[i] = 0;
  __syncthreads();

  unsigned rec[PCHUNK / 256];
  int rbkt[PCHUNK / 256];
#pragma unroll
  for (int k = 0; k < PCHUNK / 256; ++k) {
    int idx = t + k * 256;
    if (idx < nch) {
      int e = e0 + idx;
      int s = src[e];
      int d_ = dst[e];
      unsigned q = (unsigned)__float2uint_rn(w[e] * 511.f);
      rbkt[k] = d_ >> 7;
      rec[k] = ((unsigned)s << 16) | ((unsigned)(d_ & 127) << 9) | q;
      atomicAdd(&lhist[rbkt[k]], 1);
    } else {
      rbkt[k] = -1;
      rec[k] = 0;
    }
  }
  __syncthreads();

  if (t < 64) {  // exclusive scan lhist -> lstart
    int carry = 0;
    for (int base = 0; base < NBUCKET; base += 64) {
      int i = base + t;
      int v = (i < NBUCKET) ? lhist[i] : 0;
      int incl = v;
#pragma unroll
      for (int off = 1; off < 64; off <<= 1) {
        int y = __shfl_up(incl, off, 64);
        if (t >= off) incl += y;
      }
      if (i < NBUCKET) lstart[i] = incl - v + carry;
      carry += __shfl(incl, 63, 64);
    }
  }
  __syncthreads();

  for (int i = t; i < NBUCKET; i += 256) {
    gbase[i] = (lhist[i] > 0) ? atomicAdd(&gcursor[i], lhist[i]) : 0;
    lcur[i] = lstart[i];
  }
  __syncthreads();

#pragma unroll
  for (int k = 0; k < PCHUNK / 256; ++k) {
    if (rbkt[k] >= 0) {
      int lp = atomicAdd(&lcur[rbkt[k]], 1);
      staged_v[lp] = rec[k];
      staged_b[lp] = (unsigned short)rbkt[k];
    }
  }
  __syncthreads();

  for (int i = t; i < nch; i += 256) {
    int bkt = staged_b[i];
    csr4[gbase[bkt] + (i - lstart[bkt])] = staged_v[i];
  }
}

// ---------------- phase 2: place records at exact CSR slot (8KB window) ------
__global__ __launch_bounds__(256) void scatter2_kernel(const unsigned* __restrict__ csr4,
                                                       const int* __restrict__ row_start,
                                                       unsigned* __restrict__ csr_ew) {
  __shared__ int lcur[128];
  int b = blockIdx.x, t = threadIdx.x;
  if (t < 128) lcur[t] = row_start[b * 128 + t];
  __syncthreads();
  int beg = row_start[b * 128];
  int end = ((b + 1) * 128 <= N_PAD - 1) ? row_start[(b + 1) * 128] : N_EDGES;
  for (int i = beg + t; i < end; i += 256) {
    unsigned v = csr4[i];
    int nl = (v >> 9) & 127;
    int pos = atomicAdd(&lcur[nl], 1);
    csr_ew[pos] = v;
  }
}

// ---------------- aggregate: channel-split gather, XCD-pair affinity ---------
// blockIdx.x % 8 -> XCD slot; quarter q = slot>>1 lives on XCDs {2q, 2q+1},
// whose L2 then only caches quarter-table q (3.2MB < 4MB). Wave = 1 node:
// 4 sub-groups of 16 lanes process 4 edges in parallel (64B gather each).
__global__ __launch_bounds__(256) void aggregate_kernel(const unsigned* __restrict__ h_split,
                                                        const unsigned* __restrict__ csr_ew,
                                                        const int* __restrict__ row_start,
                                                        float* __restrict__ hact) {
  int bx = blockIdx.x;
  int q = (bx >> 1) & 3;
  int node = ((bx >> 3) * 2 + (bx & 1)) * 4 + (threadIdx.x >> 6);
  int lane = threadIdx.x & 63;
  int sub = lane >> 4, c = lane & 15;
  if (node >= N_NODES) return;
  int beg = row_start[node], end = row_start[node + 1];
  const float WS = 1.0f / 511.0f;
  const unsigned* hq = h_split + (size_t)q * N_NODES * 16;
  float a0 = 0.f, a1 = 0.f;
  int e = beg + sub;
  for (; e + 4 < end; e += 8) {
    unsigned pa = csr_ew[e], pb = csr_ew[e + 4];
    unsigned va = hq[(pa >> 16) * 16 + c];
    unsigned vb = hq[(pb >> 16) * 16 + c];
    float wa = (float)(pa & 0x1FFu) * WS;
    float wb = (float)(pb & 0x1FFu) * WS;
    a0 = fmaf(__uint_as_float(va << 16), wa, a0);
    a1 = fmaf(__uint_as_float(va & 0xFFFF0000u), wa, a1);
    a0 = fmaf(__uint_as_float(vb << 16), wb, a0);
    a1 = fmaf(__uint_as_float(vb & 0xFFFF0000u), wb, a1);
  }
  if (e < end) {
    unsigned p = csr_ew[e];
    unsigned v = hq[(p >> 16) * 16 + c];
    float we = (float)(p & 0x1FFu) * WS;
    a0 = fmaf(__uint_as_float(v << 16), we, a0);
    a1 = fmaf(__uint_as_float(v & 0xFFFF0000u), we, a1);
  }
  a0 += __shfl_xor(a0, 16, 64); a0 += __shfl_xor(a0, 32, 64);
  a1 += __shfl_xor(a1, 16, 64); a1 += __shfl_xor(a1, 32, 64);
  if (lane < 16) {
    int deg = end - beg;
    float inv = (deg > 0) ? 1.f / (float)deg : 0.f;
    float2 r;
    r.x = tanhf(a0 * inv);
    r.y = tanhf(a1 * inv);
    ((float2*)hact)[node * 64 + q * 16 + c] = r;
  }
}

// ---------------- out = tanh-act @ W^T + b via MFMA bf16, in place on d_out ----
__global__ __launch_bounds__(256) void gemm_kernel(const float* __restrict__ hact,
                                                   const unsigned short* __restrict__ W_bf,
                                                   const float* __restrict__ bias,
                                                   float* __restrict__ out) {
  int lane = threadIdx.x & 63;
  int wid  = threadIdx.x >> 6;
  int n_base = blockIdx.x * 64 + wid * 16;
  int m  = lane & 15;
  int kg = lane >> 4;
  int n = n_base + m;
  int n_c = (n < N_NODES) ? n : (N_NODES - 1);

  bf16x8 afrag[4];
  const float* arow = hact + (size_t)n_c * D;
#pragma unroll
  for (int kc = 0; kc < 4; ++kc) {
    int k0 = kc * 32 + kg * 8;
    float4 lo = *(const float4*)(arow + k0);
    float4 hi = *(const float4*)(arow + k0 + 4);
    bf16x8 a;
    a[0] = (short)f2bf(lo.x); a[1] = (short)f2bf(lo.y);
    a[2] = (short)f2bf(lo.z); a[3] = (short)f2bf(lo.w);
    a[4] = (short)f2bf(hi.x); a[5] = (short)f2bf(hi.y);
    a[6] = (short)f2bf(hi.z); a[7] = (short)f2bf(hi.w);
    afrag[kc] = a;
  }

#pragma unroll
  for (int jt = 0; jt < 8; ++jt) {
    int j = jt * 16 + m;
    const unsigned short* wrow = W_bf + j * D;
    f32x4 acc = {0.f, 0.f, 0.f, 0.f};
#pragma unroll
    for (int kc = 0; kc < 4; ++kc) {
      bf16x8 bb = *(const bf16x8*)(wrow + kc * 32 + kg * 8);
      acc = __builtin_amdgcn_mfma_f32_16x16x32_bf16(afrag[kc], bb, acc, 0, 0, 0);
    }
    float bj = bias[j];
#pragma unroll
    for (int rr = 0; rr < 4; ++rr) {
      int nn = n_base + kg * 4 + rr;
      if (nn < N_NODES) out[(size_t)nn * D + j] = acc[rr] + bj;
    }
  }
}

extern "C" void kernel_launch(void* const* d_in, const int* in_sizes, int n_in,
                              void* d_out, int out_size, void* d_ws, size_t ws_size,
                              hipStream_t stream) {
  const float* h    = (const float*)d_in[0];
  const float* w    = (const float*)d_in[1];
  const int*   src  = (const int*)d_in[2];
  const int*   dst  = (const int*)d_in[3];
  const float* Wm   = (const float*)d_in[4];
  const float* bias = (const float*)d_in[5];
  float* out = (float*)d_out;

  // ws layout (16B-aligned), total 19,636,288 B:
  //   count:     [0,        200704)
  //   row_start: [200704,   401408)    (padded; row_start[N] valid, flat past N)
  //   blocksum:  [401408,   401664)
  //   blockoff:  [401664,   401920)
  //   gcursor:   [401920,   403520)
  //   W_bf:      [403520,   436288)
  //   h_split:   [436288,   13236288)  (4 quarter-tables, 3.2MB each)
  //   csr4:      [13236288, 16436288)
  //   csr_ew:    [16436288, 19636288)
  char* ws = (char*)d_ws;
  int*            count     = (int*)(ws);
  int*            row_start = (int*)(ws + 200704);
  int*            blocksum  = (int*)(ws + 401408);
  int*            blockoff  = (int*)(ws + 401664);
  int*            gcursor   = (int*)(ws + 401920);
  unsigned short* W_bf      = (unsigned short*)(ws + 403520);
  unsigned*       h_split   = (unsigned*)(ws + 436288);
  unsigned*       csr4      = (unsigned*)(ws + 13236288);
  unsigned*       csr_ew    = (unsigned*)(ws + 16436288);

  hipMemsetAsync(count, 0, N_PAD * sizeof(int), stream);
  prep_kernel<<<(N_NODES * D / 4 + 255) / 256, 256, 0, stream>>>(h, h_split, dst, count);
  scan_part1<<<SCAN_BLOCKS, 256, 0, stream>>>((const int4*)count, blocksum);
  scan2_convw<<<1, 1024, 0, stream>>>(blocksum, blockoff, (const float4*)Wm, (ushort4*)W_bf);
  scan_part3<<<SCAN_BLOCKS, 256, 0, stream>>>((const int4*)count, blockoff,
                                              (int4*)row_start, gcursor);
  partition_kernel<<<NPBLK, 256, 0, stream>>>(src, dst, w, gcursor, csr4);
  scatter2_kernel<<<391, 256, 0, stream>>>(csr4, row_start, csr_ew);
  aggregate_kernel<<<50000, 256, 0, stream>>>(h_split, csr_ew, row_start, out);
  gemm_kernel<<<(N_NODES + 63) / 64, 256, 0, stream>>>(out, W_bf, bias, out);
}

// Round 8
// 140.316 us; speedup vs baseline: 1.1898x; 1.1898x over previous
//
#include <hip/hip_runtime.h>
#include <hip/hip_bf16.h>

#define N_NODES 50000
#define N_EDGES 800000
#define D 128
#define N_PAD 50176          // 392 * 128
#define NBUCKET 392          // dst >> 7 (max used: 390)
#define SCAN_BLOCKS 49
#define PCHUNK 4096
#define NPBLK ((N_EDGES + PCHUNK - 1) / PCHUNK)  // 196

typedef __attribute__((ext_vector_type(8))) short bf16x8;
typedef __attribute__((ext_vector_type(4))) float f32x4;

__device__ inline unsigned short f2bf(float f) {
  unsigned u = __float_as_uint(f);
  unsigned r = (u + 0x7FFFu + ((u >> 16) & 1u)) >> 16;
  return (unsigned short)r;
}

// ---------------- zero the histogram (replaces runtime fill node) ------------
__global__ __launch_bounds__(256) void zero_kernel(int4* __restrict__ p) {
  p[blockIdx.x * 256 + threadIdx.x] = make_int4(0, 0, 0, 0);  // 49*256*16B = 200704
}

// ---------------- prep: h f32 -> packed bf16 table, + per-node histogram ------
__global__ __launch_bounds__(256) void prep_kernel(const float* __restrict__ h,
                                                   unsigned* __restrict__ h_bf,
                                                   const int* __restrict__ dst,
                                                   int* __restrict__ count) {
  int i = blockIdx.x * blockDim.x + threadIdx.x;
  if (i < N_NODES * D / 4) {
    float4 f = ((const float4*)h)[i];
    unsigned lo = ((unsigned)f2bf(f.y) << 16) | f2bf(f.x);
    unsigned hi = ((unsigned)f2bf(f.w) << 16) | f2bf(f.z);
    ((uint2*)h_bf)[i] = make_uint2(lo, hi);
  }
  if (i < N_EDGES) atomicAdd(&count[dst[i]], 1);
}

// ---------------- scan of per-node counts (3 dispatches) ----------------

__global__ __launch_bounds__(256) void scan_part1(const int4* __restrict__ count4,
                                                  int* __restrict__ blocksum) {
  __shared__ int wsum[4];
  int b = blockIdx.x, t = threadIdx.x;
  int lane = t & 63, wid = t >> 6;
  int4 v = count4[b * 256 + t];
  int s = v.x + v.y + v.z + v.w;
#pragma unroll
  for (int off = 32; off >= 1; off >>= 1) s += __shfl_xor(s, off, 64);
  if (lane == 0) wsum[wid] = s;
  __syncthreads();
  if (t == 0) blocksum[b] = wsum[0] + wsum[1] + wsum[2] + wsum[3];
}

// wave 0: scan 49 block sums; all 1024 threads: convert W to bf16.
__global__ __launch_bounds__(1024) void scan2_convw(const int* __restrict__ blocksum,
                                                    int* __restrict__ blockoff,
                                                    const float4* __restrict__ Wm4,
                                                    ushort4* __restrict__ W4) {
  int t = threadIdx.x;
  if (t < 64) {
    int v = (t < SCAN_BLOCKS) ? blocksum[t] : 0;
    int incl = v;
#pragma unroll
    for (int off = 1; off < 64; off <<= 1) {
      int y = __shfl_up(incl, off, 64);
      if (t >= off) incl += y;
    }
    if (t < SCAN_BLOCKS) blockoff[t] = incl - v;
  }
  for (int i = t; i < D * D / 4; i += 1024) {
    float4 f = Wm4[i];
    ushort4 o;
    o.x = f2bf(f.x); o.y = f2bf(f.y); o.z = f2bf(f.z); o.w = f2bf(f.w);
    W4[i] = o;
  }
}

// row_start (padded; flat past N_NODES) + bucket cursors gcursor[b]=row_start[b*128]
__global__ __launch_bounds__(256) void scan_part3(const int4* __restrict__ count4,
                                                  const int* __restrict__ blockoff,
                                                  int4* __restrict__ row4,
                                                  int* __restrict__ gcursor) {
  __shared__ int wsum[4];
  int b = blockIdx.x, t = threadIdx.x;
  int lane = t & 63, wid = t >> 6;
  int4 v = count4[b * 256 + t];
  int s = v.x + v.y + v.z + v.w;
  int incl = s;
#pragma unroll
  for (int off = 1; off < 64; off <<= 1) {
    int y = __shfl_up(incl, off, 64);
    if (lane >= off) incl += y;
  }
  if (lane == 63) wsum[wid] = incl;
  __syncthreads();
  int woff = 0;
#pragma unroll
  for (int i = 0; i < 4; ++i) woff += (i < wid) ? wsum[i] : 0;
  int excl = incl - s + woff + blockoff[b];
  int4 p;
  p.x = excl;
  p.y = p.x + v.x;
  p.z = p.y + v.y;
  p.w = p.z + v.z;
  row4[b * 256 + t] = p;
  int node = b * 1024 + t * 4;
  if ((node & 127) == 0) gcursor[node >> 7] = p.x;
}

// ---------------- phase 1: LDS-staged partition by 128-node bucket -----------
// packed record: [src:16 | node_local:7 | w_q9:9]
__global__ __launch_bounds__(256) void partition_kernel(const int* __restrict__ src,
                                                        const int* __restrict__ dst,
                                                        const float* __restrict__ w,
                                                        int* __restrict__ gcursor,
                                                        unsigned* __restrict__ csr4) {
  __shared__ int lhist[NBUCKET];
  __shared__ int lstart[NBUCKET];
  __shared__ int lcur[NBUCKET];
  __shared__ int gbase[NBUCKET];
  __shared__ unsigned staged_v[PCHUNK];
  __shared__ unsigned short staged_b[PCHUNK];
  int t = threadIdx.x;
  int e0 = blockIdx.x * PCHUNK;
  int nch = N_EDGES - e0; if (nch > PCHUNK) nch = PCHUNK;

  for (int i = t; i < NBUCKET; i += 256) lhist[i] = 0;
  __syncthreads();

  unsigned rec[PCHUNK / 256];
  int rbkt[PCHUNK / 256];
#pragma unroll
  for (int k = 0; k < PCHUNK / 256; ++k) {
    int idx = t + k * 256;
    if (idx < nch) {
      int e = e0 + idx;
      int s = src[e];
      int d_ = dst[e];
      unsigned q = (unsigned)__float2uint_rn(w[e] * 511.f);
      rbkt[k] = d_ >> 7;
      rec[k] = ((unsigned)s << 16) | ((unsigned)(d_ & 127) << 9) | q;
      atomicAdd(&lhist[rbkt[k]], 1);
    } else {
      rbkt[k] = -1;
      rec[k] = 0;
    }
  }
  __syncthreads();

  if (t < 64) {  // exclusive scan lhist -> lstart
    int carry = 0;
    for (int base = 0; base < NBUCKET; base += 64) {
      int i = base + t;
      int v = (i < NBUCKET) ? lhist[i] : 0;
      int incl = v;
#pragma unroll
      for (int off = 1; off < 64; off <<= 1) {
        int y = __shfl_up(incl, off, 64);
        if (t >= off) incl += y;
      }
      if (i < NBUCKET) lstart[i] = incl - v + carry;
      carry += __shfl(incl, 63, 64);
    }
  }
  __syncthreads();

  for (int i = t; i < NBUCKET; i += 256) {
    gbase[i] = (lhist[i] > 0) ? atomicAdd(&gcursor[i], lhist[i]) : 0;
    lcur[i] = lstart[i];
  }
  __syncthreads();

#pragma unroll
  for (int k = 0; k < PCHUNK / 256; ++k) {
    if (rbkt[k] >= 0) {
      int lp = atomicAdd(&lcur[rbkt[k]], 1);
      staged_v[lp] = rec[k];
      staged_b[lp] = (unsigned short)rbkt[k];
    }
  }
  __syncthreads();

  for (int i = t; i < nch; i += 256) {
    int bkt = staged_b[i];
    csr4[gbase[bkt] + (i - lstart[bkt])] = staged_v[i];
  }
}

// ---------------- phase 2: place records at exact CSR slot (8KB window) ------
__global__ __launch_bounds__(256) void scatter2_kernel(const unsigned* __restrict__ csr4,
                                                       const int* __restrict__ row_start,
                                                       unsigned* __restrict__ csr_ew) {
  __shared__ int lcur[128];
  int b = blockIdx.x, t = threadIdx.x;
  if (t < 128) lcur[t] = row_start[b * 128 + t];
  __syncthreads();
  int beg = row_start[b * 128];
  int end = row_start[(b + 1) * 128];
  for (int i = beg + t; i < end; i += 256) {
    unsigned v = csr4[i];
    int nl = (v >> 9) & 127;
    int pos = atomicAdd(&lcur[nl], 1);
    csr_ew[pos] = v;
  }
}

// ---------------- aggregate: mean of h[src]*w by dst, then tanh ----------------
// One 64-lane wave per node; lane owns channels {2*lane, 2*lane+1} packed in a uint.
__global__ __launch_bounds__(256) void aggregate_kernel(const unsigned* __restrict__ h_bf,
                                                        const unsigned* __restrict__ csr_ew,
                                                        const int* __restrict__ row_start,
                                                        float* __restrict__ hact) {
  int node = blockIdx.x * 4 + (threadIdx.x >> 6);
  int lane = threadIdx.x & 63;
  if (node >= N_NODES) return;
  int beg = row_start[node], end = row_start[node + 1];
  const float WS = 1.0f / 511.0f;
  float a0 = 0.f, a1 = 0.f;
  int e = beg;
  for (; e + 4 <= end; e += 4) {
    unsigned p0 = csr_ew[e],   p1 = csr_ew[e+1], p2 = csr_ew[e+2], p3 = csr_ew[e+3];
    unsigned v0 = h_bf[(p0 >> 16) * 64 + lane];
    unsigned v1 = h_bf[(p1 >> 16) * 64 + lane];
    unsigned v2 = h_bf[(p2 >> 16) * 64 + lane];
    unsigned v3 = h_bf[(p3 >> 16) * 64 + lane];
    float w0 = (float)(p0 & 0x1FFu) * WS;
    float w1 = (float)(p1 & 0x1FFu) * WS;
    float w2 = (float)(p2 & 0x1FFu) * WS;
    float w3 = (float)(p3 & 0x1FFu) * WS;
    a0 = fmaf(__uint_as_float(v0 << 16), w0, a0);
    a1 = fmaf(__uint_as_float(v0 & 0xFFFF0000u), w0, a1);
    a0 = fmaf(__uint_as_float(v1 << 16), w1, a0);
    a1 = fmaf(__uint_as_float(v1 & 0xFFFF0000u), w1, a1);
    a0 = fmaf(__uint_as_float(v2 << 16), w2, a0);
    a1 = fmaf(__uint_as_float(v2 & 0xFFFF0000u), w2, a1);
    a0 = fmaf(__uint_as_float(v3 << 16), w3, a0);
    a1 = fmaf(__uint_as_float(v3 & 0xFFFF0000u), w3, a1);
  }
  for (; e < end; ++e) {
    unsigned p = csr_ew[e];
    unsigned v = h_bf[(p >> 16) * 64 + lane];
    float we = (float)(p & 0x1FFu) * WS;
    a0 = fmaf(__uint_as_float(v << 16), we, a0);
    a1 = fmaf(__uint_as_float(v & 0xFFFF0000u), we, a1);
  }
  int deg = end - beg;
  float inv = (deg > 0) ? 1.f / (float)deg : 0.f;
  float2 r;
  r.x = tanhf(a0 * inv);
  r.y = tanhf(a1 * inv);
  ((float2*)hact)[node * 64 + lane] = r;
}

// ---------------- out = tanh-act @ W^T + b via MFMA bf16, in place on d_out ----
__global__ __launch_bounds__(256) void gemm_kernel(const float* __restrict__ hact,
                                                   const unsigned short* __restrict__ W_bf,
                                                   const float* __restrict__ bias,
                                                   float* __restrict__ out) {
  int lane = threadIdx.x & 63;
  int wid  = threadIdx.x >> 6;
  int n_base = blockIdx.x * 64 + wid * 16;
  int m  = lane & 15;
  int kg = lane >> 4;
  int n = n_base + m;
  int n_c = (n < N_NODES) ? n : (N_NODES - 1);

  bf16x8 afrag[4];
  const float* arow = hact + (size_t)n_c * D;
#pragma unroll
  for (int kc = 0; kc < 4; ++kc) {
    int k0 = kc * 32 + kg * 8;
    float4 lo = *(const float4*)(arow + k0);
    float4 hi = *(const float4*)(arow + k0 + 4);
    bf16x8 a;
    a[0] = (short)f2bf(lo.x); a[1] = (short)f2bf(lo.y);
    a[2] = (short)f2bf(lo.z); a[3] = (short)f2bf(lo.w);
    a[4] = (short)f2bf(hi.x); a[5] = (short)f2bf(hi.y);
    a[6] = (short)f2bf(hi.z); a[7] = (short)f2bf(hi.w);
    afrag[kc] = a;
  }

#pragma unroll
  for (int jt = 0; jt < 8; ++jt) {
    int j = jt * 16 + m;
    const unsigned short* wrow = W_bf + j * D;
    f32x4 acc = {0.f, 0.f, 0.f, 0.f};
#pragma unroll
    for (int kc = 0; kc < 4; ++kc) {
      bf16x8 bb = *(const bf16x8*)(wrow + kc * 32 + kg * 8);
      acc = __builtin_amdgcn_mfma_f32_16x16x32_bf16(afrag[kc], bb, acc, 0, 0, 0);
    }
    float bj = bias[j];
#pragma unroll
    for (int rr = 0; rr < 4; ++rr) {
      int nn = n_base + kg * 4 + rr;
      if (nn < N_NODES) out[(size_t)nn * D + j] = acc[rr] + bj;
    }
  }
}

extern "C" void kernel_launch(void* const* d_in, const int* in_sizes, int n_in,
                              void* d_out, int out_size, void* d_ws, size_t ws_size,
                              hipStream_t stream) {
  const float* h    = (const float*)d_in[0];
  const float* w    = (const float*)d_in[1];
  const int*   src  = (const int*)d_in[2];
  const int*   dst  = (const int*)d_in[3];
  const float* Wm   = (const float*)d_in[4];
  const float* bias = (const float*)d_in[5];
  float* out = (float*)d_out;

  // ws layout (16B-aligned), total 19,636,288 B:
  //   count:     [0,        200704)
  //   row_start: [200704,   401408)    (padded; row_start[N] valid, flat past N)
  //   blocksum:  [401408,   401664)
  //   blockoff:  [401664,   401920)
  //   gcursor:   [401920,   403520)
  //   W_bf:      [403520,   436288)
  //   h_bf:      [436288,   13236288)  (12.8 MB)
  //   csr4:      [13236288, 16436288)
  //   csr_ew:    [16436288, 19636288)
  char* ws = (char*)d_ws;
  int*            count     = (int*)(ws);
  int*            row_start = (int*)(ws + 200704);
  int*            blocksum  = (int*)(ws + 401408);
  int*            blockoff  = (int*)(ws + 401664);
  int*            gcursor   = (int*)(ws + 401920);
  unsigned short* W_bf      = (unsigned short*)(ws + 403520);
  unsigned*       h_bf      = (unsigned*)(ws + 436288);
  unsigned*       csr4      = (unsigned*)(ws + 13236288);
  unsigned*       csr_ew    = (unsigned*)(ws + 16436288);

  zero_kernel<<<SCAN_BLOCKS, 256, 0, stream>>>((int4*)count);
  prep_kernel<<<(N_NODES * D / 4 + 255) / 256, 256, 0, stream>>>(h, h_bf, dst, count);
  scan_part1<<<SCAN_BLOCKS, 256, 0, stream>>>((const int4*)count, blocksum);
  scan2_convw<<<1, 1024, 0, stream>>>(blocksum, blockoff, (const float4*)Wm, (ushort4*)W_bf);
  scan_part3<<<SCAN_BLOCKS, 256, 0, stream>>>((const int4*)count, blockoff,
                                              (int4*)row_start, gcursor);
  partition_kernel<<<NPBLK, 256, 0, stream>>>(src, dst, w, gcursor, csr4);
  scatter2_kernel<<<391, 256, 0, stream>>>(csr4, row_start, csr_ew);
  aggregate_kernel<<<(N_NODES + 3) / 4, 256, 0, stream>>>(h_bf, csr_ew, row_start, out);
  gemm_kernel<<<(N_NODES + 63) / 64, 256, 0, stream>>>(out, W_bf, bias, out);
}

// Round 10
// 137.968 us; speedup vs baseline: 1.2100x; 1.0170x over previous
//
#include <hip/hip_runtime.h>
#include <hip/hip_bf16.h>

#define N_NODES 50000
#define N_EDGES 800000
#define D 128
#define N_PAD 50176          // 392 * 128
#define NBUCKET 392          // dst >> 7 (max used: 390)
#define SCAN_BLOCKS 49
#define PCHUNK 2048
#define NPBLK ((N_EDGES + PCHUNK - 1) / PCHUNK)  // 391

typedef __attribute__((ext_vector_type(8))) short bf16x8;
typedef __attribute__((ext_vector_type(4))) float f32x4;

__device__ inline unsigned short f2bf(float f) {
  unsigned u = __float_as_uint(f);
  unsigned r = (u + 0x7FFFu + ((u >> 16) & 1u)) >> 16;
  return (unsigned short)r;
}

// ---------------- zero the histogram ------------
__global__ __launch_bounds__(256) void zero_kernel(int4* __restrict__ p) {
  p[blockIdx.x * 256 + threadIdx.x] = make_int4(0, 0, 0, 0);  // 49*256*16B = 200704
}

// ---------------- prep: h f32 -> int8 row-scaled table (6.4MB) + scale + hist --
// One wave per node: lane l owns channels {2l, 2l+1}. scale[n] = absmax/(127*511)
// (1/511 folded in so aggregate's multiplier is scale[src]*w_q9 directly).
__global__ __launch_bounds__(256) void prep_kernel(const float* __restrict__ h,
                                                   unsigned short* __restrict__ h8,
                                                   float* __restrict__ scale,
                                                   const int* __restrict__ dst,
                                                   int* __restrict__ count) {
  int t = threadIdx.x;
  int lane = t & 63;
  int node = blockIdx.x * 4 + (t >> 6);
  if (node < N_NODES) {
    float2 f = ((const float2*)h)[node * 64 + lane];
    float A = fmaxf(fabsf(f.x), fabsf(f.y));
#pragma unroll
    for (int off = 32; off >= 1; off >>= 1) A = fmaxf(A, __shfl_xor(A, off, 64));
    float inv = (A > 0.f) ? 127.f / A : 0.f;
    int q0 = (int)rintf(f.x * inv);
    int q1 = (int)rintf(f.y * inv);
    h8[node * 64 + lane] = (unsigned short)((q0 & 0xFF) | ((q1 & 0xFF) << 8));
    if (lane == 0) scale[node] = A / (127.f * 511.f);
  }
  int i = blockIdx.x * 256 + t;
  if (i < N_EDGES) atomicAdd(&count[dst[i]], 1);
}

// ---------------- scan of per-node counts (3 dispatches) ----------------

__global__ __launch_bounds__(256) void scan_part1(const int4* __restrict__ count4,
                                                  int* __restrict__ blocksum) {
  __shared__ int wsum[4];
  int b = blockIdx.x, t = threadIdx.x;
  int lane = t & 63, wid = t >> 6;
  int4 v = count4[b * 256 + t];
  int s = v.x + v.y + v.z + v.w;
#pragma unroll
  for (int off = 32; off >= 1; off >>= 1) s += __shfl_xor(s, off, 64);
  if (lane == 0) wsum[wid] = s;
  __syncthreads();
  if (t == 0) blocksum[b] = wsum[0] + wsum[1] + wsum[2] + wsum[3];
}

// wave 0: scan 49 block sums; all 1024 threads: convert W to bf16.
__global__ __launch_bounds__(1024) void scan2_convw(const int* __restrict__ blocksum,
                                                    int* __restrict__ blockoff,
                                                    const float4* __restrict__ Wm4,
                                                    ushort4* __restrict__ W4) {
  int t = threadIdx.x;
  if (t < 64) {
    int v = (t < SCAN_BLOCKS) ? blocksum[t] : 0;
    int incl = v;
#pragma unroll
    for (int off = 1; off < 64; off <<= 1) {
      int y = __shfl_up(incl, off, 64);
      if (t >= off) incl += y;
    }
    if (t < SCAN_BLOCKS) blockoff[t] = incl - v;
  }
  for (int i = t; i < D * D / 4; i += 1024) {
    float4 f = Wm4[i];
    ushort4 o;
    o.x = f2bf(f.x); o.y = f2bf(f.y); o.z = f2bf(f.z); o.w = f2bf(f.w);
    W4[i] = o;
  }
}

// row_start (padded; flat past N_NODES) + bucket cursors gcursor[b]=row_start[b*128]
__global__ __launch_bounds__(256) void scan_part3(const int4* __restrict__ count4,
                                                  const int* __restrict__ blockoff,
                                                  int4* __restrict__ row4,
                                                  int* __restrict__ gcursor) {
  __shared__ int wsum[4];
  int b = blockIdx.x, t = threadIdx.x;
  int lane = t & 63, wid = t >> 6;
  int4 v = count4[b * 256 + t];
  int s = v.x + v.y + v.z + v.w;
  int incl = s;
#pragma unroll
  for (int off = 1; off < 64; off <<= 1) {
    int y = __shfl_up(incl, off, 64);
    if (lane >= off) incl += y;
  }
  if (lane == 63) wsum[wid] = incl;
  __syncthreads();
  int woff = 0;
#pragma unroll
  for (int i = 0; i < 4; ++i) woff += (i < wid) ? wsum[i] : 0;
  int excl = incl - s + woff + blockoff[b];
  int4 p;
  p.x = excl;
  p.y = p.x + v.x;
  p.z = p.y + v.y;
  p.w = p.z + v.z;
  row4[b * 256 + t] = p;
  int node = b * 1024 + t * 4;
  if ((node & 127) == 0) gcursor[node >> 7] = p.x;
}

// ---------------- phase 1: LDS-staged partition by 128-node bucket -----------
// packed record: [src:16 | node_local:7 | w_q9:9]
__global__ __launch_bounds__(256) void partition_kernel(const int* __restrict__ src,
                                                        const int* __restrict__ dst,
                                                        const float* __restrict__ w,
                                                        int* __restrict__ gcursor,
                                                        unsigned* __restrict__ csr4) {
  __shared__ int lhist[NBUCKET];
  __shared__ int lstart[NBUCKET];
  __shared__ int lcur[NBUCKET];
  __shared__ int gbase[NBUCKET];
  __shared__ unsigned staged_v[PCHUNK];
  __shared__ unsigned short staged_b[PCHUNK];
  int t = threadIdx.x;
  int e0 = blockIdx.x * PCHUNK;
  int nch = N_EDGES - e0; if (nch > PCHUNK) nch = PCHUNK;

  for (int i = t; i < NBUCKET; i += 256) lhist[i] = 0;
  __syncthreads();

  unsigned rec[PCHUNK / 256];
  int rbkt[PCHUNK / 256];
#pragma unroll
  for (int k = 0; k < PCHUNK / 256; ++k) {
    int idx = t + k * 256;
    if (idx < nch) {
      int e = e0 + idx;
      int s = src[e];
      int d_ = dst[e];
      unsigned q = (unsigned)__float2uint_rn(w[e] * 511.f);
      rbkt[k] = d_ >> 7;
      rec[k] = ((unsigned)s << 16) | ((unsigned)(d_ & 127) << 9) | q;
      atomicAdd(&lhist[rbkt[k]], 1);
    } else {
      rbkt[k] = -1;
      rec[k] = 0;
    }
  }
  __syncthreads();

  if (t < 64) {  // exclusive scan lhist -> lstart
    int carry = 0;
    for (int base = 0; base < NBUCKET; base += 64) {
      int i = base + t;
      int v = (i < NBUCKET) ? lhist[i] : 0;
      int incl = v;
#pragma unroll
      for (int off = 1; off < 64; off <<= 1) {
        int y = __shfl_up(incl, off, 64);
        if (t >= off) incl += y;
      }
      if (i < NBUCKET) lstart[i] = incl - v + carry;
      carry += __shfl(incl, 63, 64);
    }
  }
  __syncthreads();

  for (int i = t; i < NBUCKET; i += 256) {
    gbase[i] = (lhist[i] > 0) ? atomicAdd(&gcursor[i], lhist[i]) : 0;
    lcur[i] = lstart[i];
  }
  __syncthreads();

#pragma unroll
  for (int k = 0; k < PCHUNK / 256; ++k) {
    if (rbkt[k] >= 0) {
      int lp = atomicAdd(&lcur[rbkt[k]], 1);
      staged_v[lp] = rec[k];
      staged_b[lp] = (unsigned short)rbkt[k];
    }
  }
  __syncthreads();

  for (int i = t; i < nch; i += 256) {
    int bkt = staged_b[i];
    csr4[gbase[bkt] + (i - lstart[bkt])] = staged_v[i];
  }
}

// ---------------- phase 2: place records at exact CSR slot (8KB window) ------
__global__ __launch_bounds__(256) void scatter2_kernel(const unsigned* __restrict__ csr4,
                                                       const int* __restrict__ row_start,
                                                       unsigned* __restrict__ csr_ew) {
  __shared__ int lcur[128];
  int b = blockIdx.x, t = threadIdx.x;
  if (t < 128) lcur[t] = row_start[b * 128 + t];
  __syncthreads();
  int beg = row_start[b * 128];
  int end = row_start[(b + 1) * 128];
  for (int i = beg + t; i < end; i += 256) {
    unsigned v = csr4[i];
    int nl = (v >> 9) & 127;
    int pos = atomicAdd(&lcur[nl], 1);
    csr_ew[pos] = v;
  }
}

// ---------------- aggregate: mean of h[src]*w by dst, then tanh ----------------
// One wave per node; lane owns channels {2l,2l+1} as one ushort (2 int8).
// multiplier m = scale[src] * w_q9  (scale has 1/(127*511) folded in).
__global__ __launch_bounds__(256) void aggregate_kernel(const unsigned short* __restrict__ h8,
                                                        const float* __restrict__ scale,
                                                        const unsigned* __restrict__ csr_ew,
                                                        const int* __restrict__ row_start,
                                                        float* __restrict__ hact) {
  int node = blockIdx.x * 4 + (threadIdx.x >> 6);
  int lane = threadIdx.x & 63;
  if (node >= N_NODES) return;
  int beg = row_start[node], end = row_start[node + 1];
  float a0 = 0.f, a1 = 0.f;
  int e = beg;
  for (; e + 4 <= end; e += 4) {
    unsigned p0 = csr_ew[e],   p1 = csr_ew[e+1], p2 = csr_ew[e+2], p3 = csr_ew[e+3];
    int s0 = p0 >> 16, s1 = p1 >> 16, s2 = p2 >> 16, s3 = p3 >> 16;
    unsigned short v0 = h8[s0 * 64 + lane];
    unsigned short v1 = h8[s1 * 64 + lane];
    unsigned short v2 = h8[s2 * 64 + lane];
    unsigned short v3 = h8[s3 * 64 + lane];
    float m0 = scale[s0] * (float)(p0 & 0x1FFu);
    float m1 = scale[s1] * (float)(p1 & 0x1FFu);
    float m2 = scale[s2] * (float)(p2 & 0x1FFu);
    float m3 = scale[s3] * (float)(p3 & 0x1FFu);
    a0 = fmaf((float)(signed char)(v0 & 0xFF), m0, a0);
    a1 = fmaf((float)(signed char)(v0 >> 8),   m0, a1);
    a0 = fmaf((float)(signed char)(v1 & 0xFF), m1, a0);
    a1 = fmaf((float)(signed char)(v1 >> 8),   m1, a1);
    a0 = fmaf((float)(signed char)(v2 & 0xFF), m2, a0);
    a1 = fmaf((float)(signed char)(v2 >> 8),   m2, a1);
    a0 = fmaf((float)(signed char)(v3 & 0xFF), m3, a0);
    a1 = fmaf((float)(signed char)(v3 >> 8),   m3, a1);
  }
  for (; e < end; ++e) {
    unsigned p = csr_ew[e];
    int s = p >> 16;
    unsigned short v = h8[s * 64 + lane];
    float m = scale[s] * (float)(p & 0x1FFu);
    a0 = fmaf((float)(signed char)(v & 0xFF), m, a0);
    a1 = fmaf((float)(signed char)(v >> 8),   m, a1);
  }
  int deg = end - beg;
  float inv = (deg > 0) ? 1.f / (float)deg : 0.f;
  float2 r;
  r.x = tanhf(a0 * inv);
  r.y = tanhf(a1 * inv);
  ((float2*)hact)[node * 64 + lane] = r;
}

// ---------------- out = tanh-act @ W^T + b via MFMA bf16, in place on d_out ----
__global__ __launch_bounds__(256) void gemm_kernel(const float* __restrict__ hact,
                                                   const unsigned short* __restrict__ W_bf,
                                                   const float* __restrict__ bias,
                                                   float* __restrict__ out) {
  int lane = threadIdx.x & 63;
  int wid  = threadIdx.x >> 6;
  int n_base = blockIdx.x * 64 + wid * 16;
  int m  = lane & 15;
  int kg = lane >> 4;
  int n = n_base + m;
  int n_c = (n < N_NODES) ? n : (N_NODES - 1);

  bf16x8 afrag[4];
  const float* arow = hact + (size_t)n_c * D;
#pragma unroll
  for (int kc = 0; kc < 4; ++kc) {
    int k0 = kc * 32 + kg * 8;
    float4 lo = *(const float4*)(arow + k0);
    float4 hi = *(const float4*)(arow + k0 + 4);
    bf16x8 a;
    a[0] = (short)f2bf(lo.x); a[1] = (short)f2bf(lo.y);
    a[2] = (short)f2bf(lo.z); a[3] = (short)f2bf(lo.w);
    a[4] = (short)f2bf(hi.x); a[5] = (short)f2bf(hi.y);
    a[6] = (short)f2bf(hi.z); a[7] = (short)f2bf(hi.w);
    afrag[kc] = a;
  }

#pragma unroll
  for (int jt = 0; jt < 8; ++jt) {
    int j = jt * 16 + m;
    const unsigned short* wrow = W_bf + j * D;
    f32x4 acc = {0.f, 0.f, 0.f, 0.f};
#pragma unroll
    for (int kc = 0; kc < 4; ++kc) {
      bf16x8 bb = *(const bf16x8*)(wrow + kc * 32 + kg * 8);
      acc = __builtin_amdgcn_mfma_f32_16x16x32_bf16(afrag[kc], bb, acc, 0, 0, 0);
    }
    float bj = bias[j];
#pragma unroll
    for (int rr = 0; rr < 4; ++rr) {
      int nn = n_base + kg * 4 + rr;
      if (nn < N_NODES) out[(size_t)nn * D + j] = acc[rr] + bj;
    }
  }
}

extern "C" void kernel_launch(void* const* d_in, const int* in_sizes, int n_in,
                              void* d_out, int out_size, void* d_ws, size_t ws_size,
                              hipStream_t stream) {
  const float* h    = (const float*)d_in[0];
  const float* w    = (const float*)d_in[1];
  const int*   src  = (const int*)d_in[2];
  const int*   dst  = (const int*)d_in[3];
  const float* Wm   = (const float*)d_in[4];
  const float* bias = (const float*)d_in[5];
  float* out = (float*)d_out;

  // ws layout (16B-aligned), total ~13.9 MB (< proven 19.6MB budget):
  //   count:     [0,        200704)
  //   row_start: [200704,   401408)    (padded; row_start[N] valid, flat past N)
  //   blocksum:  [401408,   401664)
  //   blockoff:  [401664,   401920)
  //   gcursor:   [401920,   403520)
  //   W_bf:      [403520,   436288)
  //   scale:     [436288,   636288)    (50000 f32, padded to 16B)
  //   h8:        [636288,   7036288)   (6.4 MB int8 row-scaled, 2B per lane)
  //   csr4:      [7036288,  10236288)
  //   csr_ew:    [10236288, 13436288)
  char* ws = (char*)d_ws;
  int*            count     = (int*)(ws);
  int*            row_start = (int*)(ws + 200704);
  int*            blocksum  = (int*)(ws + 401408);
  int*            blockoff  = (int*)(ws + 401664);
  int*            gcursor   = (int*)(ws + 401920);
  unsigned short* W_bf      = (unsigned short*)(ws + 403520);
  float*          scale     = (float*)(ws + 436288);
  unsigned short* h8        = (unsigned short*)(ws + 636288);
  unsigned*       csr4      = (unsigned*)(ws + 7036288);
  unsigned*       csr_ew    = (unsigned*)(ws + 10236288);

  zero_kernel<<<SCAN_BLOCKS, 256, 0, stream>>>((int4*)count);
  prep_kernel<<<(N_NODES + 3) / 4, 256, 0, stream>>>(h, h8, scale, dst, count);
  scan_part1<<<SCAN_BLOCKS, 256, 0, stream>>>((const int4*)count, blocksum);
  scan2_convw<<<1, 1024, 0, stream>>>(blocksum, blockoff, (const float4*)Wm, (ushort4*)W_bf);
  scan_part3<<<SCAN_BLOCKS, 256, 0, stream>>>((const int4*)count, blockoff,
                                              (int4*)row_start, gcursor);
  partition_kernel<<<NPBLK, 256, 0, stream>>>(src, dst, w, gcursor, csr4);
  scatter2_kernel<<<391, 256, 0, stream>>>(csr4, row_start, csr_ew);
  aggregate_kernel<<<(N_NODES + 3) / 4, 256, 0, stream>>>(h8, scale, csr_ew, row_start, out);
  gemm_kernel<<<(N_NODES + 63) / 64, 256, 0, stream>>>(out, W_bf, bias, out);
}

// Round 11
// 117.409 us; speedup vs baseline: 1.4219x; 1.1751x over previous
//
#include <hip/hip_runtime.h>
#include <hip/hip_bf16.h>

#define N_NODES 50000
#define N_EDGES 800000
#define D 128
#define N_PAD 50176          // 392 * 128
#define NBUCKET 392          // dst >> 7 (max used: 390)
#define PCHUNK 2048
#define NPBLK ((N_EDGES + PCHUNK - 1) / PCHUNK)  // 391

typedef __attribute__((ext_vector_type(8))) short bf16x8;
typedef __attribute__((ext_vector_type(4))) float f32x4;

__device__ inline unsigned short f2bf(float f) {
  unsigned u = __float_as_uint(f);
  unsigned r = (u + 0x7FFFu + ((u >> 16) & 1u)) >> 16;
  return (unsigned short)r;
}

// ---------------- zero bucket_count (392 ints) ----------------
__global__ __launch_bounds__(256) void zero_kernel(int4* __restrict__ p) {
  int t = threadIdx.x;
  if (t < 98) p[t] = make_int4(0, 0, 0, 0);
}

// ---------------- prep: h f32 -> int8 row-scaled table + scale (pure stream) --
// 32-lane group per node row: lane g holds channels {4g..4g+3} via float4.
__global__ __launch_bounds__(256) void prep_kernel(const float* __restrict__ h,
                                                   unsigned* __restrict__ h8,
                                                   float* __restrict__ scale) {
  int t = threadIdx.x;
  int g = t & 31;
  int node = blockIdx.x * 8 + (t >> 5);
  if (node >= N_NODES) return;
  float4 f = ((const float4*)h)[node * 32 + g];
  float A = fmaxf(fmaxf(fabsf(f.x), fabsf(f.y)), fmaxf(fabsf(f.z), fabsf(f.w)));
#pragma unroll
  for (int off = 16; off >= 1; off >>= 1) A = fmaxf(A, __shfl_xor(A, off, 64));
  float inv = (A > 0.f) ? 127.f / A : 0.f;
  int q0 = (int)rintf(f.x * inv);
  int q1 = (int)rintf(f.y * inv);
  int q2 = (int)rintf(f.z * inv);
  int q3 = (int)rintf(f.w * inv);
  h8[node * 32 + g] = (unsigned)(q0 & 0xFF) | ((unsigned)(q1 & 0xFF) << 8) |
                      ((unsigned)(q2 & 0xFF) << 16) | ((unsigned)(q3 & 0xFF) << 24);
  if (g == 0) scale[node] = A / (127.f * 511.f);
}

// ---------------- bucket histogram: LDS-privatized, 392 bins -----------------
__global__ __launch_bounds__(256) void bhist_kernel(const int* __restrict__ dst,
                                                    int* __restrict__ bucket_count) {
  __shared__ int lh[NBUCKET];
  int t = threadIdx.x;
  for (int i = t; i < NBUCKET; i += 256) lh[i] = 0;
  __syncthreads();
  for (int i = blockIdx.x * 256 + t; i < N_EDGES; i += gridDim.x * 256)
    atomicAdd(&lh[dst[i] >> 7], 1);
  __syncthreads();
  for (int i = t; i < NBUCKET; i += 256)
    if (lh[i]) atomicAdd(&bucket_count[i], lh[i]);
}

// wave 0: exclusive scan of 392 bucket counts -> bstart & gcursor;
// all 1024 threads: convert W to bf16.
__global__ __launch_bounds__(1024) void scan_convw(const int* __restrict__ bucket_count,
                                                   int* __restrict__ bstart,
                                                   int* __restrict__ gcursor,
                                                   const float4* __restrict__ Wm4,
                                                   ushort4* __restrict__ W4) {
  int t = threadIdx.x;
  if (t < 64) {
    int carry = 0;
    for (int base = 0; base < NBUCKET; base += 64) {
      int i = base + t;
      int v = (i < NBUCKET) ? bucket_count[i] : 0;
      int incl = v;
#pragma unroll
      for (int off = 1; off < 64; off <<= 1) {
        int y = __shfl_up(incl, off, 64);
        if (t >= off) incl += y;
      }
      int excl = incl - v + carry;
      if (i < NBUCKET) { bstart[i] = excl; gcursor[i] = excl; }
      carry += __shfl(incl, 63, 64);
    }
    if (t == 0) bstart[NBUCKET] = carry;
  }
  for (int i = t; i < D * D / 4; i += 1024) {
    float4 f = Wm4[i];
    ushort4 o;
    o.x = f2bf(f.x); o.y = f2bf(f.y); o.z = f2bf(f.z); o.w = f2bf(f.w);
    W4[i] = o;
  }
}

// ---------------- phase 1: LDS-staged partition by 128-node bucket -----------
// packed record: [src:16 | node_local:7 | w_q9:9]
__global__ __launch_bounds__(256) void partition_kernel(const int* __restrict__ src,
                                                        const int* __restrict__ dst,
                                                        const float* __restrict__ w,
                                                        int* __restrict__ gcursor,
                                                        unsigned* __restrict__ csr4) {
  __shared__ int lhist[NBUCKET];
  __shared__ int lstart[NBUCKET];
  __shared__ int lcur[NBUCKET];
  __shared__ int gbase[NBUCKET];
  __shared__ unsigned staged_v[PCHUNK];
  __shared__ unsigned short staged_b[PCHUNK];
  int t = threadIdx.x;
  int e0 = blockIdx.x * PCHUNK;
  int nch = N_EDGES - e0; if (nch > PCHUNK) nch = PCHUNK;

  for (int i = t; i < NBUCKET; i += 256) lhist[i] = 0;
  __syncthreads();

  unsigned rec[PCHUNK / 256];
  int rbkt[PCHUNK / 256];
#pragma unroll
  for (int k = 0; k < PCHUNK / 256; ++k) {
    int idx = t + k * 256;
    if (idx < nch) {
      int e = e0 + idx;
      int s = src[e];
      int d_ = dst[e];
      unsigned q = (unsigned)__float2uint_rn(w[e] * 511.f);
      rbkt[k] = d_ >> 7;
      rec[k] = ((unsigned)s << 16) | ((unsigned)(d_ & 127) << 9) | q;
      atomicAdd(&lhist[rbkt[k]], 1);
    } else {
      rbkt[k] = -1;
      rec[k] = 0;
    }
  }
  __syncthreads();

  if (t < 64) {  // exclusive scan lhist -> lstart
    int carry = 0;
    for (int base = 0; base < NBUCKET; base += 64) {
      int i = base + t;
      int v = (i < NBUCKET) ? lhist[i] : 0;
      int incl = v;
#pragma unroll
      for (int off = 1; off < 64; off <<= 1) {
        int y = __shfl_up(incl, off, 64);
        if (t >= off) incl += y;
      }
      if (i < NBUCKET) lstart[i] = incl - v + carry;
      carry += __shfl(incl, 63, 64);
    }
  }
  __syncthreads();

  for (int i = t; i < NBUCKET; i += 256) {
    gbase[i] = (lhist[i] > 0) ? atomicAdd(&gcursor[i], lhist[i]) : 0;
    lcur[i] = lstart[i];
  }
  __syncthreads();

#pragma unroll
  for (int k = 0; k < PCHUNK / 256; ++k) {
    if (rbkt[k] >= 0) {
      int lp = atomicAdd(&lcur[rbkt[k]], 1);
      staged_v[lp] = rec[k];
      staged_b[lp] = (unsigned short)rbkt[k];
    }
  }
  __syncthreads();

  for (int i = t; i < nch; i += 256) {
    int bkt = staged_b[i];
    csr4[gbase[bkt] + (i - lstart[bkt])] = staged_v[i];
  }
}

// ---------------- phase 2: per-bucket node count + scan + exact placement ----
// Derives per-node row_start from the bucket-grouped records (no global hist).
__global__ __launch_bounds__(256) void scatter2_kernel(const unsigned* __restrict__ csr4,
                                                       const int* __restrict__ bstart,
                                                       int* __restrict__ row_start,
                                                       unsigned* __restrict__ csr_ew) {
  __shared__ int cnt[128];
  __shared__ int base[128];
  int b = blockIdx.x, t = threadIdx.x;
  if (t < 128) cnt[t] = 0;
  __syncthreads();
  int beg = bstart[b], end = bstart[b + 1];
  for (int i = beg + t; i < end; i += 256)
    atomicAdd(&cnt[(csr4[i] >> 9) & 127], 1);
  __syncthreads();
  if (t < 64) {  // exclusive scan of 128 bins (2 chunks, wave 0)
    int carry = beg;
    for (int c = 0; c < 2; ++c) {
      int v = cnt[c * 64 + t];
      int incl = v;
#pragma unroll
      for (int off = 1; off < 64; off <<= 1) {
        int y = __shfl_up(incl, off, 64);
        if (t >= off) incl += y;
      }
      base[c * 64 + t] = incl - v + carry;
      carry += __shfl(incl, 63, 64);
    }
  }
  __syncthreads();
  if (t < 128) { row_start[b * 128 + t] = base[t]; cnt[t] = base[t]; }
  __syncthreads();
  for (int i = beg + t; i < end; i += 256) {
    unsigned v = csr4[i];
    int pos = atomicAdd(&cnt[(v >> 9) & 127], 1);
    csr_ew[pos] = v;
  }
}

// ---------------- aggregate: mean of h[src]*w by dst, then tanh ----------------
// One wave per node; lane owns channels {2l,2l+1} as one ushort (2 int8).
// multiplier m = scale[src] * w_q9  (scale has 1/(127*511) folded in).
__global__ __launch_bounds__(256) void aggregate_kernel(const unsigned short* __restrict__ h8,
                                                        const float* __restrict__ scale,
                                                        const unsigned* __restrict__ csr_ew,
                                                        const int* __restrict__ row_start,
                                                        float* __restrict__ hact) {
  int node = blockIdx.x * 4 + (threadIdx.x >> 6);
  int lane = threadIdx.x & 63;
  if (node >= N_NODES) return;
  int beg = row_start[node], end = row_start[node + 1];
  float a0 = 0.f, a1 = 0.f;
  int e = beg;
  for (; e + 4 <= end; e += 4) {
    unsigned p0 = csr_ew[e],   p1 = csr_ew[e+1], p2 = csr_ew[e+2], p3 = csr_ew[e+3];
    int s0 = p0 >> 16, s1 = p1 >> 16, s2 = p2 >> 16, s3 = p3 >> 16;
    unsigned short v0 = h8[s0 * 64 + lane];
    unsigned short v1 = h8[s1 * 64 + lane];
    unsigned short v2 = h8[s2 * 64 + lane];
    unsigned short v3 = h8[s3 * 64 + lane];
    float m0 = scale[s0] * (float)(p0 & 0x1FFu);
    float m1 = scale[s1] * (float)(p1 & 0x1FFu);
    float m2 = scale[s2] * (float)(p2 & 0x1FFu);
    float m3 = scale[s3] * (float)(p3 & 0x1FFu);
    a0 = fmaf((float)(signed char)(v0 & 0xFF), m0, a0);
    a1 = fmaf((float)(signed char)(v0 >> 8),   m0, a1);
    a0 = fmaf((float)(signed char)(v1 & 0xFF), m1, a0);
    a1 = fmaf((float)(signed char)(v1 >> 8),   m1, a1);
    a0 = fmaf((float)(signed char)(v2 & 0xFF), m2, a0);
    a1 = fmaf((float)(signed char)(v2 >> 8),   m2, a1);
    a0 = fmaf((float)(signed char)(v3 & 0xFF), m3, a0);
    a1 = fmaf((float)(signed char)(v3 >> 8),   m3, a1);
  }
  for (; e < end; ++e) {
    unsigned p = csr_ew[e];
    int s = p >> 16;
    unsigned short v = h8[s * 64 + lane];
    float m = scale[s] * (float)(p & 0x1FFu);
    a0 = fmaf((float)(signed char)(v & 0xFF), m, a0);
    a1 = fmaf((float)(signed char)(v >> 8),   m, a1);
  }
  int deg = end - beg;
  float inv = (deg > 0) ? 1.f / (float)deg : 0.f;
  float2 r;
  r.x = tanhf(a0 * inv);
  r.y = tanhf(a1 * inv);
  ((float2*)hact)[node * 64 + lane] = r;
}

// ---------------- out = tanh-act @ W^T + b via MFMA bf16, in place on d_out ----
__global__ __launch_bounds__(256) void gemm_kernel(const float* __restrict__ hact,
                                                   const unsigned short* __restrict__ W_bf,
                                                   const float* __restrict__ bias,
                                                   float* __restrict__ out) {
  int lane = threadIdx.x & 63;
  int wid  = threadIdx.x >> 6;
  int n_base = blockIdx.x * 64 + wid * 16;
  int m  = lane & 15;
  int kg = lane >> 4;
  int n = n_base + m;
  int n_c = (n < N_NODES) ? n : (N_NODES - 1);

  bf16x8 afrag[4];
  const float* arow = hact + (size_t)n_c * D;
#pragma unroll
  for (int kc = 0; kc < 4; ++kc) {
    int k0 = kc * 32 + kg * 8;
    float4 lo = *(const float4*)(arow + k0);
    float4 hi = *(const float4*)(arow + k0 + 4);
    bf16x8 a;
    a[0] = (short)f2bf(lo.x); a[1] = (short)f2bf(lo.y);
    a[2] = (short)f2bf(lo.z); a[3] = (short)f2bf(lo.w);
    a[4] = (short)f2bf(hi.x); a[5] = (short)f2bf(hi.y);
    a[6] = (short)f2bf(hi.z); a[7] = (short)f2bf(hi.w);
    afrag[kc] = a;
  }

#pragma unroll
  for (int jt = 0; jt < 8; ++jt) {
    int j = jt * 16 + m;
    const unsigned short* wrow = W_bf + j * D;
    f32x4 acc = {0.f, 0.f, 0.f, 0.f};
#pragma unroll
    for (int kc = 0; kc < 4; ++kc) {
      bf16x8 bb = *(const bf16x8*)(wrow + kc * 32 + kg * 8);
      acc = __builtin_amdgcn_mfma_f32_16x16x32_bf16(afrag[kc], bb, acc, 0, 0, 0);
    }
    float bj = bias[j];
#pragma unroll
    for (int rr = 0; rr < 4; ++rr) {
      int nn = n_base + kg * 4 + rr;
      if (nn < N_NODES) out[(size_t)nn * D + j] = acc[rr] + bj;
    }
  }
}

extern "C" void kernel_launch(void* const* d_in, const int* in_sizes, int n_in,
                              void* d_out, int out_size, void* d_ws, size_t ws_size,
                              hipStream_t stream) {
  const float* h    = (const float*)d_in[0];
  const float* w    = (const float*)d_in[1];
  const int*   src  = (const int*)d_in[2];
  const int*   dst  = (const int*)d_in[3];
  const float* Wm   = (const float*)d_in[4];
  const float* bias = (const float*)d_in[5];
  float* out = (float*)d_out;

  // ws layout (16B-aligned), total ~13.24 MB:
  //   bucket_count: [0,       1600)     (392 ints)
  //   bstart:       [1600,    3184)     (393 ints)
  //   gcursor:      [3184,    4800)     (392 ints)
  //   W_bf:         [4800,    37568)
  //   scale:        [37568,   237568)   (50000 f32)
  //   h8:           [237568,  6637568)  (6.4 MB int8 row-scaled)
  //   row_start:    [6637568, 6838272)  (N_PAD ints; [0..50047] written)
  //   csr4:         [6838272, 10038272)
  //   csr_ew:       [10038272,13238272)
  char* ws = (char*)d_ws;
  int*            bucket_count = (int*)(ws);
  int*            bstart       = (int*)(ws + 1600);
  int*            gcursor      = (int*)(ws + 3184);
  unsigned short* W_bf         = (unsigned short*)(ws + 4800);
  float*          scale        = (float*)(ws + 37568);
  unsigned*       h8           = (unsigned*)(ws + 237568);
  int*            row_start    = (int*)(ws + 6637568);
  unsigned*       csr4         = (unsigned*)(ws + 6838272);
  unsigned*       csr_ew       = (unsigned*)(ws + 10038272);

  zero_kernel<<<1, 256, 0, stream>>>((int4*)bucket_count);
  prep_kernel<<<(N_NODES + 7) / 8, 256, 0, stream>>>(h, h8, scale);
  bhist_kernel<<<391, 256, 0, stream>>>(dst, bucket_count);
  scan_convw<<<1, 1024, 0, stream>>>(bucket_count, bstart, gcursor, (const float4*)Wm, (ushort4*)W_bf);
  partition_kernel<<<NPBLK, 256, 0, stream>>>(src, dst, w, gcursor, csr4);
  scatter2_kernel<<<391, 256, 0, stream>>>(csr4, bstart, row_start, csr_ew);
  aggregate_kernel<<<(N_NODES + 3) / 4, 256, 0, stream>>>((const unsigned short*)h8, scale, csr_ew, row_start, out);
  gemm_kernel<<<(N_NODES + 63) / 64, 256, 0, stream>>>(out, W_bf, bias, out);
}

// Round 12
// 105.511 us; speedup vs baseline: 1.5822x; 1.1128x over previous
//
#include <hip/hip_runtime.h>
#include <hip/hip_bf16.h>

#define N_NODES 50000
#define N_EDGES 800000
#define D 128
#define N_PAD 50176          // 392 * 128
#define NBUCKET 392          // dst >> 7 (max used: 390)
#define PCHUNK 2048
#define NPBLK ((N_EDGES + PCHUNK - 1) / PCHUNK)  // 391

typedef __attribute__((ext_vector_type(8))) short bf16x8;
typedef __attribute__((ext_vector_type(4))) float f32x4;

__device__ inline unsigned short f2bf(float f) {
  unsigned u = __float_as_uint(f);
  unsigned r = (u + 0x7FFFu + ((u >> 16) & 1u)) >> 16;
  return (unsigned short)r;
}

// ---------------- prep: h f32 -> int8 row-scaled table + scale (pure stream) --
// 32-lane group per node row: lane g holds channels {4g..4g+3} via float4.
// Block 0 also zeroes bucket_count (completes before bhist launches).
__global__ __launch_bounds__(256) void prep_kernel(const float* __restrict__ h,
                                                   unsigned* __restrict__ h8,
                                                   float* __restrict__ scale,
                                                   int4* __restrict__ bucket_count4) {
  int t = threadIdx.x;
  if (blockIdx.x == 0 && t < 98) bucket_count4[t] = make_int4(0, 0, 0, 0);
  int g = t & 31;
  int node = blockIdx.x * 8 + (t >> 5);
  if (node >= N_NODES) return;
  float4 f = ((const float4*)h)[node * 32 + g];
  float A = fmaxf(fmaxf(fabsf(f.x), fabsf(f.y)), fmaxf(fabsf(f.z), fabsf(f.w)));
#pragma unroll
  for (int off = 16; off >= 1; off >>= 1) A = fmaxf(A, __shfl_xor(A, off, 64));
  float inv = (A > 0.f) ? 127.f / A : 0.f;
  int q0 = (int)rintf(f.x * inv);
  int q1 = (int)rintf(f.y * inv);
  int q2 = (int)rintf(f.z * inv);
  int q3 = (int)rintf(f.w * inv);
  h8[node * 32 + g] = (unsigned)(q0 & 0xFF) | ((unsigned)(q1 & 0xFF) << 8) |
                      ((unsigned)(q2 & 0xFF) << 16) | ((unsigned)(q3 & 0xFF) << 24);
  if (g == 0) scale[node] = A / (127.f * 511.f);
}

// ---------------- bucket histogram: LDS-privatized, 392 bins -----------------
__global__ __launch_bounds__(256) void bhist_kernel(const int* __restrict__ dst,
                                                    int* __restrict__ bucket_count) {
  __shared__ int lh[NBUCKET];
  int t = threadIdx.x;
  for (int i = t; i < NBUCKET; i += 256) lh[i] = 0;
  __syncthreads();
  for (int i = blockIdx.x * 256 + t; i < N_EDGES; i += gridDim.x * 256)
    atomicAdd(&lh[dst[i] >> 7], 1);
  __syncthreads();
  for (int i = t; i < NBUCKET; i += 256)
    if (lh[i]) atomicAdd(&bucket_count[i], lh[i]);
}

// wave 0: exclusive scan of 392 bucket counts -> bstart & gcursor;
// all 1024 threads: convert W to bf16.
__global__ __launch_bounds__(1024) void scan_convw(const int* __restrict__ bucket_count,
                                                   int* __restrict__ bstart,
                                                   int* __restrict__ gcursor,
                                                   const float4* __restrict__ Wm4,
                                                   ushort4* __restrict__ W4) {
  int t = threadIdx.x;
  if (t < 64) {
    int carry = 0;
    for (int base = 0; base < NBUCKET; base += 64) {
      int i = base + t;
      int v = (i < NBUCKET) ? bucket_count[i] : 0;
      int incl = v;
#pragma unroll
      for (int off = 1; off < 64; off <<= 1) {
        int y = __shfl_up(incl, off, 64);
        if (t >= off) incl += y;
      }
      int excl = incl - v + carry;
      if (i < NBUCKET) { bstart[i] = excl; gcursor[i] = excl; }
      carry += __shfl(incl, 63, 64);
    }
    if (t == 0) bstart[NBUCKET] = carry;
  }
  for (int i = t; i < D * D / 4; i += 1024) {
    float4 f = Wm4[i];
    ushort4 o;
    o.x = f2bf(f.x); o.y = f2bf(f.y); o.z = f2bf(f.z); o.w = f2bf(f.w);
    W4[i] = o;
  }
}

// ---------------- phase 1: LDS-staged partition by 128-node bucket -----------
// packed record: [src:16 | node_local:7 | w_q9:9]
__global__ __launch_bounds__(256) void partition_kernel(const int* __restrict__ src,
                                                        const int* __restrict__ dst,
                                                        const float* __restrict__ w,
                                                        int* __restrict__ gcursor,
                                                        unsigned* __restrict__ csr4) {
  __shared__ int lhist[NBUCKET];
  __shared__ int lstart[NBUCKET];
  __shared__ int lcur[NBUCKET];
  __shared__ int gbase[NBUCKET];
  __shared__ unsigned staged_v[PCHUNK];
  __shared__ unsigned short staged_b[PCHUNK];
  int t = threadIdx.x;
  int e0 = blockIdx.x * PCHUNK;
  int nch = N_EDGES - e0; if (nch > PCHUNK) nch = PCHUNK;

  for (int i = t; i < NBUCKET; i += 256) lhist[i] = 0;
  __syncthreads();

  unsigned rec[PCHUNK / 256];
  int rbkt[PCHUNK / 256];
#pragma unroll
  for (int k = 0; k < PCHUNK / 256; ++k) {
    int idx = t + k * 256;
    if (idx < nch) {
      int e = e0 + idx;
      int s = src[e];
      int d_ = dst[e];
      unsigned q = (unsigned)__float2uint_rn(w[e] * 511.f);
      rbkt[k] = d_ >> 7;
      rec[k] = ((unsigned)s << 16) | ((unsigned)(d_ & 127) << 9) | q;
      atomicAdd(&lhist[rbkt[k]], 1);
    } else {
      rbkt[k] = -1;
      rec[k] = 0;
    }
  }
  __syncthreads();

  if (t < 64) {  // exclusive scan lhist -> lstart
    int carry = 0;
    for (int base = 0; base < NBUCKET; base += 64) {
      int i = base + t;
      int v = (i < NBUCKET) ? lhist[i] : 0;
      int incl = v;
#pragma unroll
      for (int off = 1; off < 64; off <<= 1) {
        int y = __shfl_up(incl, off, 64);
        if (t >= off) incl += y;
      }
      if (i < NBUCKET) lstart[i] = incl - v + carry;
      carry += __shfl(incl, 63, 64);
    }
  }
  __syncthreads();

  for (int i = t; i < NBUCKET; i += 256) {
    gbase[i] = (lhist[i] > 0) ? atomicAdd(&gcursor[i], lhist[i]) : 0;
    lcur[i] = lstart[i];
  }
  __syncthreads();

#pragma unroll
  for (int k = 0; k < PCHUNK / 256; ++k) {
    if (rbkt[k] >= 0) {
      int lp = atomicAdd(&lcur[rbkt[k]], 1);
      staged_v[lp] = rec[k];
      staged_b[lp] = (unsigned short)rbkt[k];
    }
  }
  __syncthreads();

  for (int i = t; i < nch; i += 256) {
    int bkt = staged_b[i];
    csr4[gbase[bkt] + (i - lstart[bkt])] = staged_v[i];
  }
}

// ---------------- phase 2: per-bucket node count + scan + exact placement ----
__global__ __launch_bounds__(256) void scatter2_kernel(const unsigned* __restrict__ csr4,
                                                       const int* __restrict__ bstart,
                                                       int* __restrict__ row_start,
                                                       unsigned* __restrict__ csr_ew) {
  __shared__ int cnt[128];
  __shared__ int base[128];
  int b = blockIdx.x, t = threadIdx.x;
  if (t < 128) cnt[t] = 0;
  __syncthreads();
  int beg = bstart[b], end = bstart[b + 1];
  for (int i = beg + t; i < end; i += 256)
    atomicAdd(&cnt[(csr4[i] >> 9) & 127], 1);
  __syncthreads();
  if (t < 64) {  // exclusive scan of 128 bins (2 chunks, wave 0)
    int carry = beg;
    for (int c = 0; c < 2; ++c) {
      int v = cnt[c * 64 + t];
      int incl = v;
#pragma unroll
      for (int off = 1; off < 64; off <<= 1) {
        int y = __shfl_up(incl, off, 64);
        if (t >= off) incl += y;
      }
      base[c * 64 + t] = incl - v + carry;
      carry += __shfl(incl, 63, 64);
    }
  }
  __syncthreads();
  if (t < 128) { row_start[b * 128 + t] = base[t]; cnt[t] = base[t]; }
  __syncthreads();
  for (int i = beg + t; i < end; i += 256) {
    unsigned v = csr4[i];
    int pos = atomicAdd(&cnt[(v >> 9) & 127], 1);
    csr_ew[pos] = v;
  }
}

// ---------------- aggregate: mean of h[src]*w by dst, then tanh -> bf16 ------
// Wave per node; 2 edges in flight: lanes 0-31 edge e, lanes 32-63 edge e+1.
// Lane g owns channels {4g..4g+3} (one uint = 4 int8). Output: bf16 row
// written into d_out at byte offset node*512 (first half of its f32 slot).
__global__ __launch_bounds__(256) void aggregate_kernel(const unsigned* __restrict__ h8,
                                                        const float* __restrict__ scale,
                                                        const unsigned* __restrict__ csr_ew,
                                                        const int* __restrict__ row_start,
                                                        char* __restrict__ hact_bytes) {
  int node = blockIdx.x * 4 + (threadIdx.x >> 6);
  int lane = threadIdx.x & 63;
  int g = lane & 31, half = lane >> 5;
  if (node >= N_NODES) return;
  int beg = row_start[node], end = row_start[node + 1];
  float a0 = 0.f, a1 = 0.f, a2 = 0.f, a3 = 0.f;
  int e = beg + half;
  for (; e + 2 < end; e += 4) {
    unsigned p0 = csr_ew[e], p1 = csr_ew[e + 2];
    int s0 = p0 >> 16, s1 = p1 >> 16;
    unsigned v0 = h8[s0 * 32 + g];
    unsigned v1 = h8[s1 * 32 + g];
    float m0 = scale[s0] * (float)(p0 & 0x1FFu);
    float m1 = scale[s1] * (float)(p1 & 0x1FFu);
    a0 = fmaf((float)(signed char)(v0 & 0xFF),  m0, a0);
    a1 = fmaf((float)(signed char)((v0 >> 8) & 0xFF), m0, a1);
    a2 = fmaf((float)(signed char)((v0 >> 16) & 0xFF), m0, a2);
    a3 = fmaf((float)(signed char)(v0 >> 24), m0, a3);
    a0 = fmaf((float)(signed char)(v1 & 0xFF),  m1, a0);
    a1 = fmaf((float)(signed char)((v1 >> 8) & 0xFF), m1, a1);
    a2 = fmaf((float)(signed char)((v1 >> 16) & 0xFF), m1, a2);
    a3 = fmaf((float)(signed char)(v1 >> 24), m1, a3);
  }
  if (e < end) {
    unsigned p = csr_ew[e];
    int s = p >> 16;
    unsigned v = h8[s * 32 + g];
    float m = scale[s] * (float)(p & 0x1FFu);
    a0 = fmaf((float)(signed char)(v & 0xFF),  m, a0);
    a1 = fmaf((float)(signed char)((v >> 8) & 0xFF), m, a1);
    a2 = fmaf((float)(signed char)((v >> 16) & 0xFF), m, a2);
    a3 = fmaf((float)(signed char)(v >> 24), m, a3);
  }
  a0 += __shfl_xor(a0, 32, 64);
  a1 += __shfl_xor(a1, 32, 64);
  a2 += __shfl_xor(a2, 32, 64);
  a3 += __shfl_xor(a3, 32, 64);
  if (half == 0) {
    int deg = end - beg;
    float inv = (deg > 0) ? 1.f / (float)deg : 0.f;
    float t0 = tanhf(a0 * inv), t1 = tanhf(a1 * inv);
    float t2 = tanhf(a2 * inv), t3 = tanhf(a3 * inv);
    uint2 r;
    r.x = (unsigned)f2bf(t0) | ((unsigned)f2bf(t1) << 16);
    r.y = (unsigned)f2bf(t2) | ((unsigned)f2bf(t3) << 16);
    ((uint2*)(hact_bytes + (size_t)node * 512))[g] = r;
  }
}

// ---------------- out = hact_bf16 @ W^T + b via MFMA, in place on d_out ------
// hact row n = 256 bf16 at byte n*512 (strided inside d_out). Each wave reads
// only its own 16 rows' bf16 before overwriting those rows with f32 output.
__global__ __launch_bounds__(256) void gemm_kernel(const unsigned short* __restrict__ hact_bf,
                                                   const unsigned short* __restrict__ W_bf,
                                                   const float* __restrict__ bias,
                                                   float* __restrict__ out) {
  int lane = threadIdx.x & 63;
  int wid  = threadIdx.x >> 6;
  int n_base = blockIdx.x * 64 + wid * 16;
  int m  = lane & 15;
  int kg = lane >> 4;
  int n = n_base + m;
  int n_c = (n < N_NODES) ? n : (N_NODES - 1);

  bf16x8 afrag[4];
  const unsigned short* arow = hact_bf + (size_t)n_c * 256;  // 512B stride
#pragma unroll
  for (int kc = 0; kc < 4; ++kc)
    afrag[kc] = *(const bf16x8*)(arow + kc * 32 + kg * 8);

#pragma unroll
  for (int jt = 0; jt < 8; ++jt) {
    int j = jt * 16 + m;
    const unsigned short* wrow = W_bf + j * D;
    f32x4 acc = {0.f, 0.f, 0.f, 0.f};
#pragma unroll
    for (int kc = 0; kc < 4; ++kc) {
      bf16x8 bb = *(const bf16x8*)(wrow + kc * 32 + kg * 8);
      acc = __builtin_amdgcn_mfma_f32_16x16x32_bf16(afrag[kc], bb, acc, 0, 0, 0);
    }
    float bj = bias[j];
#pragma unroll
    for (int rr = 0; rr < 4; ++rr) {
      int nn = n_base + kg * 4 + rr;
      if (nn < N_NODES) out[(size_t)nn * D + j] = acc[rr] + bj;
    }
  }
}

extern "C" void kernel_launch(void* const* d_in, const int* in_sizes, int n_in,
                              void* d_out, int out_size, void* d_ws, size_t ws_size,
                              hipStream_t stream) {
  const float* h    = (const float*)d_in[0];
  const float* w    = (const float*)d_in[1];
  const int*   src  = (const int*)d_in[2];
  const int*   dst  = (const int*)d_in[3];
  const float* Wm   = (const float*)d_in[4];
  const float* bias = (const float*)d_in[5];
  float* out = (float*)d_out;

  // ws layout (16B-aligned), total ~13.24 MB:
  //   bucket_count: [0,       1600)     (392 ints)
  //   bstart:       [1600,    3184)     (393 ints)
  //   gcursor:      [3184,    4800)     (392 ints)
  //   W_bf:         [4800,    37568)
  //   scale:        [37568,   237568)   (50000 f32)
  //   h8:           [237568,  6637568)  (6.4 MB int8 row-scaled)
  //   row_start:    [6637568, 6838272)  (N_PAD ints; [0..50047] written)
  //   csr4:         [6838272, 10038272)
  //   csr_ew:       [10038272,13238272)
  char* ws = (char*)d_ws;
  int*            bucket_count = (int*)(ws);
  int*            bstart       = (int*)(ws + 1600);
  int*            gcursor      = (int*)(ws + 3184);
  unsigned short* W_bf         = (unsigned short*)(ws + 4800);
  float*          scale        = (float*)(ws + 37568);
  unsigned*       h8           = (unsigned*)(ws + 237568);
  int*            row_start    = (int*)(ws + 6637568);
  unsigned*       csr4         = (unsigned*)(ws + 6838272);
  unsigned*       csr_ew       = (unsigned*)(ws + 10038272);

  prep_kernel<<<(N_NODES + 7) / 8, 256, 0, stream>>>(h, h8, scale, (int4*)bucket_count);
  bhist_kernel<<<391, 256, 0, stream>>>(dst, bucket_count);
  scan_convw<<<1, 1024, 0, stream>>>(bucket_count, bstart, gcursor, (const float4*)Wm, (ushort4*)W_bf);
  partition_kernel<<<NPBLK, 256, 0, stream>>>(src, dst, w, gcursor, csr4);
  scatter2_kernel<<<391, 256, 0, stream>>>(csr4, bstart, row_start, csr_ew);
  aggregate_kernel<<<(N_NODES + 3) / 4, 256, 0, stream>>>(h8, scale, csr_ew, row_start, (char*)d_out);
  gemm_kernel<<<(N_NODES + 63) / 64, 256, 0, stream>>>((const unsigned short*)d_out, W_bf, bias, out);
}

// Round 13
// 93.712 us; speedup vs baseline: 1.7815x; 1.1259x over previous
//
#include <hip/hip_runtime.h>
#include <hip/hip_bf16.h>

#define N_NODES 50000
#define N_EDGES 800000
#define D 128
#define N_PAD 50176          // 392 * 128
#define NBUCKET 392          // dst >> 7 (max used: 390)
#define PCHUNK 2048
#define NPBLK ((N_EDGES + PCHUNK - 1) / PCHUNK)  // 391

typedef __attribute__((ext_vector_type(8))) short bf16x8;
typedef __attribute__((ext_vector_type(4))) float f32x4;

__device__ inline unsigned short f2bf(float f) {
  unsigned u = __float_as_uint(f);
  unsigned r = (u + 0x7FFFu + ((u >> 16) & 1u)) >> 16;
  return (unsigned short)r;
}

// ---------------- prep: h f32 -> int8 row-scaled table + scale (pure stream) --
// 32-lane group per node row: lane g holds channels {4g..4g+3} via float4.
// Block 0 also zeroes bucket_count (completes before bhist launches).
__global__ __launch_bounds__(256) void prep_kernel(const float* __restrict__ h,
                                                   unsigned* __restrict__ h8,
                                                   float* __restrict__ scale,
                                                   int4* __restrict__ bucket_count4) {
  int t = threadIdx.x;
  if (blockIdx.x == 0 && t < 98) bucket_count4[t] = make_int4(0, 0, 0, 0);
  int g = t & 31;
  int node = blockIdx.x * 8 + (t >> 5);
  if (node >= N_NODES) return;
  float4 f = ((const float4*)h)[node * 32 + g];
  float A = fmaxf(fmaxf(fabsf(f.x), fabsf(f.y)), fmaxf(fabsf(f.z), fabsf(f.w)));
#pragma unroll
  for (int off = 16; off >= 1; off >>= 1) A = fmaxf(A, __shfl_xor(A, off, 64));
  float inv = (A > 0.f) ? 127.f / A : 0.f;
  int q0 = (int)rintf(f.x * inv);
  int q1 = (int)rintf(f.y * inv);
  int q2 = (int)rintf(f.z * inv);
  int q3 = (int)rintf(f.w * inv);
  h8[node * 32 + g] = (unsigned)(q0 & 0xFF) | ((unsigned)(q1 & 0xFF) << 8) |
                      ((unsigned)(q2 & 0xFF) << 16) | ((unsigned)(q3 & 0xFF) << 24);
  if (g == 0) scale[node] = A / (127.f * 511.f);
}

// ---------------- bucket histogram: LDS-privatized, 392 bins -----------------
__global__ __launch_bounds__(256) void bhist_kernel(const int* __restrict__ dst,
                                                    int* __restrict__ bucket_count) {
  __shared__ int lh[NBUCKET];
  int t = threadIdx.x;
  for (int i = t; i < NBUCKET; i += 256) lh[i] = 0;
  __syncthreads();
  for (int i = blockIdx.x * 256 + t; i < N_EDGES; i += gridDim.x * 256)
    atomicAdd(&lh[dst[i] >> 7], 1);
  __syncthreads();
  for (int i = t; i < NBUCKET; i += 256)
    if (lh[i]) atomicAdd(&bucket_count[i], lh[i]);
}

// wave 0: exclusive scan of 392 bucket counts -> bstart & gcursor;
// all 1024 threads: convert W to bf16.
__global__ __launch_bounds__(1024) void scan_convw(const int* __restrict__ bucket_count,
                                                   int* __restrict__ bstart,
                                                   int* __restrict__ gcursor,
                                                   const float4* __restrict__ Wm4,
                                                   ushort4* __restrict__ W4) {
  int t = threadIdx.x;
  if (t < 64) {
    int carry = 0;
    for (int base = 0; base < NBUCKET; base += 64) {
      int i = base + t;
      int v = (i < NBUCKET) ? bucket_count[i] : 0;
      int incl = v;
#pragma unroll
      for (int off = 1; off < 64; off <<= 1) {
        int y = __shfl_up(incl, off, 64);
        if (t >= off) incl += y;
      }
      int excl = incl - v + carry;
      if (i < NBUCKET) { bstart[i] = excl; gcursor[i] = excl; }
      carry += __shfl(incl, 63, 64);
    }
    if (t == 0) bstart[NBUCKET] = carry;
  }
  for (int i = t; i < D * D / 4; i += 1024) {
    float4 f = Wm4[i];
    ushort4 o;
    o.x = f2bf(f.x); o.y = f2bf(f.y); o.z = f2bf(f.z); o.w = f2bf(f.w);
    W4[i] = o;
  }
}

// ---------------- phase 1: LDS-staged partition by 128-node bucket -----------
// packed record: [src:16 | node_local:7 | w_q9:9]
__global__ __launch_bounds__(256) void partition_kernel(const int* __restrict__ src,
                                                        const int* __restrict__ dst,
                                                        const float* __restrict__ w,
                                                        int* __restrict__ gcursor,
                                                        unsigned* __restrict__ csr4) {
  __shared__ int lhist[NBUCKET];
  __shared__ int lstart[NBUCKET];
  __shared__ int lcur[NBUCKET];
  __shared__ int gbase[NBUCKET];
  __shared__ unsigned staged_v[PCHUNK];
  __shared__ unsigned short staged_b[PCHUNK];
  int t = threadIdx.x;
  int e0 = blockIdx.x * PCHUNK;
  int nch = N_EDGES - e0; if (nch > PCHUNK) nch = PCHUNK;

  for (int i = t; i < NBUCKET; i += 256) lhist[i] = 0;
  __syncthreads();

  unsigned rec[PCHUNK / 256];
  int rbkt[PCHUNK / 256];
#pragma unroll
  for (int k = 0; k < PCHUNK / 256; ++k) {
    int idx = t + k * 256;
    if (idx < nch) {
      int e = e0 + idx;
      int s = src[e];
      int d_ = dst[e];
      unsigned q = (unsigned)__float2uint_rn(w[e] * 511.f);
      rbkt[k] = d_ >> 7;
      rec[k] = ((unsigned)s << 16) | ((unsigned)(d_ & 127) << 9) | q;
      atomicAdd(&lhist[rbkt[k]], 1);
    } else {
      rbkt[k] = -1;
      rec[k] = 0;
    }
  }
  __syncthreads();

  if (t < 64) {  // exclusive scan lhist -> lstart
    int carry = 0;
    for (int base = 0; base < NBUCKET; base += 64) {
      int i = base + t;
      int v = (i < NBUCKET) ? lhist[i] : 0;
      int incl = v;
#pragma unroll
      for (int off = 1; off < 64; off <<= 1) {
        int y = __shfl_up(incl, off, 64);
        if (t >= off) incl += y;
      }
      if (i < NBUCKET) lstart[i] = incl - v + carry;
      carry += __shfl(incl, 63, 64);
    }
  }
  __syncthreads();

  for (int i = t; i < NBUCKET; i += 256) {
    gbase[i] = (lhist[i] > 0) ? atomicAdd(&gcursor[i], lhist[i]) : 0;
    lcur[i] = lstart[i];
  }
  __syncthreads();

#pragma unroll
  for (int k = 0; k < PCHUNK / 256; ++k) {
    if (rbkt[k] >= 0) {
      int lp = atomicAdd(&lcur[rbkt[k]], 1);
      staged_v[lp] = rec[k];
      staged_b[lp] = (unsigned short)rbkt[k];
    }
  }
  __syncthreads();

  for (int i = t; i < nch; i += 256) {
    int bkt = staged_b[i];
    csr4[gbase[bkt] + (i - lstart[bkt])] = staged_v[i];
  }
}

// ---------------- phase 2: per-bucket node count + scan + exact placement ----
__global__ __launch_bounds__(256) void scatter2_kernel(const unsigned* __restrict__ csr4,
                                                       const int* __restrict__ bstart,
                                                       int* __restrict__ row_start,
                                                       unsigned* __restrict__ csr_ew) {
  __shared__ int cnt[128];
  __shared__ int base[128];
  int b = blockIdx.x, t = threadIdx.x;
  if (t < 128) cnt[t] = 0;
  __syncthreads();
  int beg = bstart[b], end = bstart[b + 1];
  for (int i = beg + t; i < end; i += 256)
    atomicAdd(&cnt[(csr4[i] >> 9) & 127], 1);
  __syncthreads();
  if (t < 64) {  // exclusive scan of 128 bins (2 chunks, wave 0)
    int carry = beg;
    for (int c = 0; c < 2; ++c) {
      int v = cnt[c * 64 + t];
      int incl = v;
#pragma unroll
      for (int off = 1; off < 64; off <<= 1) {
        int y = __shfl_up(incl, off, 64);
        if (t >= off) incl += y;
      }
      base[c * 64 + t] = incl - v + carry;
      carry += __shfl(incl, 63, 64);
    }
  }
  __syncthreads();
  if (t < 128) { row_start[b * 128 + t] = base[t]; cnt[t] = base[t]; }
  __syncthreads();
  for (int i = beg + t; i < end; i += 256) {
    unsigned v = csr4[i];
    int pos = atomicAdd(&cnt[(v >> 9) & 127], 1);
    csr_ew[pos] = v;
  }
}

// ---------------- fused aggregate + GEMM -------------------------------------
// Block = 16 nodes (3125 blocks, 256 threads, 4 waves).
// Phase A: wave w aggregates nodes {16*blk + 4w .. +3}; quarter-wave edge
//   parallelism (16 lanes/edge, 8 ch/lane via uint2, 4 edges in flight, x2
//   unroll). Reduce via shfl_xor(16,32); each lane tanh+packs 2 channels to
//   LDS bf16 tile [16][136] (272B row stride -> 2-way banks, free).
// Phase B: wave w computes j-tiles {2w, 2w+1} with MFMA from the LDS tile.
__global__ __launch_bounds__(256) void agg_gemm_kernel(const uint2* __restrict__ h8,
                                                       const float* __restrict__ scale,
                                                       const unsigned* __restrict__ csr_ew,
                                                       const int* __restrict__ row_start,
                                                       const unsigned short* __restrict__ W_bf,
                                                       const float* __restrict__ bias,
                                                       float* __restrict__ out) {
  __shared__ unsigned short hact[16][136];
  int t = threadIdx.x;
  int lane = t & 63, wid = t >> 6;
  int q = lane >> 4, c = lane & 15;
  int n0 = blockIdx.x * 16;

#pragma unroll
  for (int i = 0; i < 4; ++i) {
    int node = n0 + wid * 4 + i;
    int beg = row_start[node], end = row_start[node + 1];
    float a[8] = {0.f, 0.f, 0.f, 0.f, 0.f, 0.f, 0.f, 0.f};
    int e = beg + q;
    for (; e + 4 < end; e += 8) {
      unsigned p0 = csr_ew[e], p1 = csr_ew[e + 4];
      int s0 = p0 >> 16, s1 = p1 >> 16;
      uint2 v0 = h8[s0 * 16 + c];
      uint2 v1 = h8[s1 * 16 + c];
      float m0 = scale[s0] * (float)(p0 & 0x1FFu);
      float m1 = scale[s1] * (float)(p1 & 0x1FFu);
      a[0] = fmaf((float)(signed char)(v0.x & 0xFF), m0, a[0]);
      a[1] = fmaf((float)(signed char)((v0.x >> 8) & 0xFF), m0, a[1]);
      a[2] = fmaf((float)(signed char)((v0.x >> 16) & 0xFF), m0, a[2]);
      a[3] = fmaf((float)(signed char)(v0.x >> 24), m0, a[3]);
      a[4] = fmaf((float)(signed char)(v0.y & 0xFF), m0, a[4]);
      a[5] = fmaf((float)(signed char)((v0.y >> 8) & 0xFF), m0, a[5]);
      a[6] = fmaf((float)(signed char)((v0.y >> 16) & 0xFF), m0, a[6]);
      a[7] = fmaf((float)(signed char)(v0.y >> 24), m0, a[7]);
      a[0] = fmaf((float)(signed char)(v1.x & 0xFF), m1, a[0]);
      a[1] = fmaf((float)(signed char)((v1.x >> 8) & 0xFF), m1, a[1]);
      a[2] = fmaf((float)(signed char)((v1.x >> 16) & 0xFF), m1, a[2]);
      a[3] = fmaf((float)(signed char)(v1.x >> 24), m1, a[3]);
      a[4] = fmaf((float)(signed char)(v1.y & 0xFF), m1, a[4]);
      a[5] = fmaf((float)(signed char)((v1.y >> 8) & 0xFF), m1, a[5]);
      a[6] = fmaf((float)(signed char)((v1.y >> 16) & 0xFF), m1, a[6]);
      a[7] = fmaf((float)(signed char)(v1.y >> 24), m1, a[7]);
    }
    if (e < end) {
      unsigned p = csr_ew[e];
      int s = p >> 16;
      uint2 v = h8[s * 16 + c];
      float m = scale[s] * (float)(p & 0x1FFu);
      a[0] = fmaf((float)(signed char)(v.x & 0xFF), m, a[0]);
      a[1] = fmaf((float)(signed char)((v.x >> 8) & 0xFF), m, a[1]);
      a[2] = fmaf((float)(signed char)((v.x >> 16) & 0xFF), m, a[2]);
      a[3] = fmaf((float)(signed char)(v.x >> 24), m, a[3]);
      a[4] = fmaf((float)(signed char)(v.y & 0xFF), m, a[4]);
      a[5] = fmaf((float)(signed char)((v.y >> 8) & 0xFF), m, a[5]);
      a[6] = fmaf((float)(signed char)((v.y >> 16) & 0xFF), m, a[6]);
      a[7] = fmaf((float)(signed char)(v.y >> 24), m, a[7]);
    }
#pragma unroll
    for (int k = 0; k < 8; ++k) {
      a[k] += __shfl_xor(a[k], 16, 64);
      a[k] += __shfl_xor(a[k], 32, 64);
    }
    int deg = end - beg;
    float inv = (deg > 0) ? 1.f / (float)deg : 0.f;
    // lane (q,c) owns channels {8c+2q, 8c+2q+1}
    float t0 = tanhf(a[2 * q] * inv);
    float t1 = tanhf(a[2 * q + 1] * inv);
    unsigned r = (unsigned)f2bf(t0) | ((unsigned)f2bf(t1) << 16);
    *(unsigned*)&hact[wid * 4 + i][c * 8 + q * 2] = r;
  }
  __syncthreads();

  // ---- Phase B: GEMM from LDS tile; wave wid handles jt = 2*wid, 2*wid+1 ----
  int m = lane & 15;
  int kg = lane >> 4;
  bf16x8 afrag[4];
#pragma unroll
  for (int kc = 0; kc < 4; ++kc)
    afrag[kc] = *(const bf16x8*)&hact[m][kc * 32 + kg * 8];

#pragma unroll
  for (int jj = 0; jj < 2; ++jj) {
    int jt = wid * 2 + jj;
    int j = jt * 16 + m;
    const unsigned short* wrow = W_bf + j * D;
    f32x4 acc = {0.f, 0.f, 0.f, 0.f};
#pragma unroll
    for (int kc = 0; kc < 4; ++kc) {
      bf16x8 bb = *(const bf16x8*)(wrow + kc * 32 + kg * 8);
      acc = __builtin_amdgcn_mfma_f32_16x16x32_bf16(afrag[kc], bb, acc, 0, 0, 0);
    }
    float bj = bias[j];
#pragma unroll
    for (int rr = 0; rr < 4; ++rr) {
      int nn = n0 + kg * 4 + rr;
      out[(size_t)nn * D + j] = acc[rr] + bj;
    }
  }
}

extern "C" void kernel_launch(void* const* d_in, const int* in_sizes, int n_in,
                              void* d_out, int out_size, void* d_ws, size_t ws_size,
                              hipStream_t stream) {
  const float* h    = (const float*)d_in[0];
  const float* w    = (const float*)d_in[1];
  const int*   src  = (const int*)d_in[2];
  const int*   dst  = (const int*)d_in[3];
  const float* Wm   = (const float*)d_in[4];
  const float* bias = (const float*)d_in[5];
  float* out = (float*)d_out;

  // ws layout (16B-aligned), total ~13.24 MB:
  //   bucket_count: [0,       1600)     (392 ints)
  //   bstart:       [1600,    3184)     (393 ints)
  //   gcursor:      [3184,    4800)     (392 ints)
  //   W_bf:         [4800,    37568)
  //   scale:        [37568,   237568)   (50000 f32)
  //   h8:           [237568,  6637568)  (6.4 MB int8 row-scaled)
  //   row_start:    [6637568, 6838272)  (N_PAD ints; [0..50047] written)
  //   csr4:         [6838272, 10038272)
  //   csr_ew:       [10038272,13238272)
  char* ws = (char*)d_ws;
  int*            bucket_count = (int*)(ws);
  int*            bstart       = (int*)(ws + 1600);
  int*            gcursor      = (int*)(ws + 3184);
  unsigned short* W_bf         = (unsigned short*)(ws + 4800);
  float*          scale        = (float*)(ws + 37568);
  unsigned*       h8           = (unsigned*)(ws + 237568);
  int*            row_start    = (int*)(ws + 6637568);
  unsigned*       csr4         = (unsigned*)(ws + 6838272);
  unsigned*       csr_ew       = (unsigned*)(ws + 10038272);

  prep_kernel<<<(N_NODES + 7) / 8, 256, 0, stream>>>(h, h8, scale, (int4*)bucket_count);
  bhist_kernel<<<391, 256, 0, stream>>>(dst, bucket_count);
  scan_convw<<<1, 1024, 0, stream>>>(bucket_count, bstart, gcursor, (const float4*)Wm, (ushort4*)W_bf);
  partition_kernel<<<NPBLK, 256, 0, stream>>>(src, dst, w, gcursor, csr4);
  scatter2_kernel<<<391, 256, 0, stream>>>(csr4, bstart, row_start, csr_ew);
  agg_gemm_kernel<<<N_NODES / 16, 256, 0, stream>>>((const uint2*)h8, scale, csr_ew,
                                                    row_start, W_bf, bias, out);
}